// Round 1
// baseline (3499.022 us; speedup 1.0000x reference)
//
#include <hip/hip_runtime.h>
#include <math.h>

#define N_TOK 8192
#define D_FEAT 768
#define K_EIG 256
#define KNN 10
#define CAP 256
#define NCHUNK 4
#define CHUNK_COLS 2048
#define ROWS_PB 64
#define COLT 64
#define DK 16
#define LDST 68

// ---------- top-10 insertion (static indices, sorted descending) ----------
__device__ inline void insert10(float (&v)[10], int (&ix)[10], float nv, int ni) {
  if (nv <= v[9]) return;
  bool carry = false;
#pragma unroll
  for (int s = 0; s < 10; ++s) {
    const bool doSwap = carry || (nv > v[s]);
    if (doSwap) {
      const float tvv = v[s]; const int tii = ix[s];
      v[s] = nv; ix[s] = ni;
      nv = tvv; ni = tii;
      carry = true;
    }
  }
}

// ---------- kernel 1: row-normalize FF, compute sq ----------
__global__ __launch_bounds__(256) void k_norm(const float* __restrict__ FF,
                                              float* __restrict__ FFn,
                                              float* __restrict__ sqv) {
  const int row = blockIdx.x;
  const int tid = threadIdx.x;
  const float* src = FF + (size_t)row * D_FEAT;
  float s = 0.f;
  for (int i = tid; i < D_FEAT; i += 256) { const float v = src[i]; s += v * v; }
  __shared__ float red[4];
  for (int m = 32; m > 0; m >>= 1) s += __shfl_xor(s, m, 64);
  if ((tid & 63) == 0) red[tid >> 6] = s;
  __syncthreads();
  const float tot = red[0] + red[1] + red[2] + red[3];
  const float scale = 1.f / fmaxf(sqrtf(tot), 1e-12f);
  float s2 = 0.f;
  float* dst = FFn + (size_t)row * D_FEAT;
  for (int i = tid; i < D_FEAT; i += 256) {
    const float v = src[i] * scale;
    dst[i] = v;
    s2 += v * v;
  }
  for (int m = 32; m > 0; m >>= 1) s2 += __shfl_xor(s2, m, 64);
  __syncthreads();
  if ((tid & 63) == 0) red[tid >> 6] = s2;
  __syncthreads();
  if (tid == 0) sqv[row] = red[0] + red[1] + red[2] + red[3];
}

// ---------- kernel 2: tiled dot-product scan + per-chunk top-10 ----------
__global__ __launch_bounds__(256) void k_gram_topk(const float* __restrict__ FFn,
                                                   float* __restrict__ pd,
                                                   int* __restrict__ pi) {
  __shared__ float smem[10240];  // 40KB: staging (2 bufs A+B) then merge buffer
  const int tid = threadIdx.x;
  const int rb = blockIdx.x >> 2;
  const int chunk = blockIdx.x & 3;
  const int rbase = rb * ROWS_PB;
  const int cbase = chunk * CHUNK_COLS;
  const int rp = tid >> 3;   // 0..31 -> rows rp*2, rp*2+1
  const int cg = tid & 7;    // 0..7  -> cols cg*8..cg*8+7
  const int kq = tid & 3;    // staging: k-quad
  const int srow = tid >> 2; // staging: tile row 0..63

  float d0[10], d1[10]; int j0[10], j1[10];
#pragma unroll
  for (int s = 0; s < 10; ++s) { d0[s] = -1e30f; d1[s] = -1e30f; j0[s] = -1; j1[s] = -1; }

  for (int ct = 0; ct < CHUNK_COLS / COLT; ++ct) {
    const int ctile = cbase + ct * COLT;
    float acc0[8], acc1[8];
#pragma unroll
    for (int c = 0; c < 8; ++c) { acc0[c] = 0.f; acc1[c] = 0.f; }

    // prologue: stage kt=0 into buf 0
    float4 na = *(const float4*)&FFn[(size_t)(rbase + srow) * D_FEAT + kq * 4];
    float4 nb = *(const float4*)&FFn[(size_t)(ctile + srow) * D_FEAT + kq * 4];
    {
      float* As = smem;
      float* Bs = smem + 2 * DK * LDST;
#pragma unroll
      for (int j = 0; j < 4; ++j) {
        As[(kq * 4 + j) * LDST + srow] = ((const float*)&na)[j];
        Bs[(kq * 4 + j) * LDST + srow] = ((const float*)&nb)[j];
      }
    }
    int buf = 0;
    for (int kt = 0; kt < D_FEAT / DK; ++kt) {
      __syncthreads();
      const bool more = (kt + 1 < D_FEAT / DK);
      if (more) {
        na = *(const float4*)&FFn[(size_t)(rbase + srow) * D_FEAT + (kt + 1) * DK + kq * 4];
        nb = *(const float4*)&FFn[(size_t)(ctile + srow) * D_FEAT + (kt + 1) * DK + kq * 4];
      }
      const float* As = smem + buf * DK * LDST;
      const float* Bs = smem + 2 * DK * LDST + buf * DK * LDST;
#pragma unroll
      for (int kk = 0; kk < DK; ++kk) {
        const float2 a = *(const float2*)&As[kk * LDST + rp * 2];
        const float4 b0 = *(const float4*)&Bs[kk * LDST + cg * 8];
        const float4 b1 = *(const float4*)&Bs[kk * LDST + cg * 8 + 4];
        acc0[0] += a.x * b0.x; acc0[1] += a.x * b0.y; acc0[2] += a.x * b0.z; acc0[3] += a.x * b0.w;
        acc0[4] += a.x * b1.x; acc0[5] += a.x * b1.y; acc0[6] += a.x * b1.z; acc0[7] += a.x * b1.w;
        acc1[0] += a.y * b0.x; acc1[1] += a.y * b0.y; acc1[2] += a.y * b0.z; acc1[3] += a.y * b0.w;
        acc1[4] += a.y * b1.x; acc1[5] += a.y * b1.y; acc1[6] += a.y * b1.z; acc1[7] += a.y * b1.w;
      }
      if (more) {
        float* As2 = smem + (buf ^ 1) * DK * LDST;
        float* Bs2 = smem + 2 * DK * LDST + (buf ^ 1) * DK * LDST;
#pragma unroll
        for (int j = 0; j < 4; ++j) {
          As2[(kq * 4 + j) * LDST + srow] = ((const float*)&na)[j];
          Bs2[(kq * 4 + j) * LDST + srow] = ((const float*)&nb)[j];
        }
        buf ^= 1;
      }
    }
    // fold this tile's values into per-thread top-10
#pragma unroll
    for (int c = 0; c < 8; ++c) {
      const int col = ctile + cg * 8 + c;
      insert10(d0, j0, acc0[c], col);
      insert10(d1, j1, acc1[c], col);
    }
  }

  // in-block merge: 8 threads x 10 entries per row -> top-10 per row
  __syncthreads();
  float* mD = smem;                 // [64][80]
  int* mI = (int*)(smem + 64 * 80); // [64][80]
#pragma unroll
  for (int s = 0; s < 10; ++s) {
    mD[(rp * 2 + 0) * 80 + cg * 10 + s] = d0[s]; mI[(rp * 2 + 0) * 80 + cg * 10 + s] = j0[s];
    mD[(rp * 2 + 1) * 80 + cg * 10 + s] = d1[s]; mI[(rp * 2 + 1) * 80 + cg * 10 + s] = j1[s];
  }
  __syncthreads();
  if (tid < 64) {
    float bd[10]; int bi[10];
#pragma unroll
    for (int s = 0; s < 10; ++s) { bd[s] = -1e30f; bi[s] = -1; }
    for (int e = 0; e < 80; ++e) insert10(bd, bi, mD[tid * 80 + e], mI[tid * 80 + e]);
    const int rg = rbase + tid;
#pragma unroll
    for (int s = 0; s < 10; ++s) {
      pd[((size_t)rg * NCHUNK + chunk) * KNN + s] = bd[s];
      pi[((size_t)rg * NCHUNK + chunk) * KNN + s] = bi[s];
    }
  }
}

// ---------- kernel 3: merge 4 chunk-lists per row, compute exp values ----------
__global__ void k_mergefinal(const float* __restrict__ pd, const int* __restrict__ pi,
                             const float* __restrict__ sqv,
                             float* __restrict__ tv, int* __restrict__ tj) {
  const int row = blockIdx.x * blockDim.x + threadIdx.x;
  if (row >= N_TOK) return;
  float bd[10]; int bi[10];
#pragma unroll
  for (int s = 0; s < 10; ++s) { bd[s] = -1e30f; bi[s] = -1; }
  for (int e = 0; e < NCHUNK * KNN; ++e)
    insert10(bd, bi, pd[(size_t)row * NCHUNK * KNN + e], pi[(size_t)row * NCHUNK * KNN + e]);
  const float si = sqv[row];
#pragma unroll
  for (int s = 0; s < 10; ++s) {
    const int j = bi[s];
    tv[(size_t)row * KNN + s] = expf(-0.5f * (si + sqv[j] - 2.f * bd[s]));
    tj[(size_t)row * KNN + s] = j;
  }
}

// ---------- kernel 4: scatter both edge directions into per-row lists ----------
__global__ void k_scatter(const float* __restrict__ tv, const int* __restrict__ tj,
                          int* __restrict__ cnt, int* __restrict__ nbrJ,
                          float* __restrict__ nbrW) {
  const int e = blockIdx.x * blockDim.x + threadIdx.x;
  if (e >= N_TOK * KNN) return;
  const int i = e / KNN;
  const int j = tj[e];
  if (j == i) return;  // diagonal zeroed in gram
  const float w = 0.5f * tv[e];
  const int p = atomicAdd(&cnt[i], 1);
  if (p < CAP) { nbrJ[(size_t)i * CAP + p] = j; nbrW[(size_t)i * CAP + p] = w; }
  const int q = atomicAdd(&cnt[j], 1);
  if (q < CAP) { nbrJ[(size_t)j * CAP + q] = i; nbrW[(size_t)j * CAP + q] = w; }
}

// ---------- kernel 5: degree + rsqrt ----------
__global__ void k_degree(const int* __restrict__ cnt, const float* __restrict__ nbrW,
                         float* __restrict__ Dv) {
  const int r = blockIdx.x * 4 + (threadIdx.x >> 6);
  const int lane = threadIdx.x & 63;
  const int c = min(cnt[r], CAP);
  float s = 0.f;
  for (int m = lane; m < c; m += 64) s += nbrW[(size_t)r * CAP + m];
  for (int m = 32; m > 0; m >>= 1) s += __shfl_xor(s, m, 64);
  if (lane == 0) Dv[r] = (s > 0.f) ? rsqrtf(s) : 0.f;
}

// ---------- kernel 6: gPsi = (D gram D) @ Psi  (sparse rows) ----------
__global__ __launch_bounds__(256) void k_gpsi(const float* __restrict__ Psi,
                                              const int* __restrict__ cnt,
                                              const int* __restrict__ nbrJ,
                                              const float* __restrict__ nbrW,
                                              const float* __restrict__ Dv,
                                              float* __restrict__ gP) {
  const int i = blockIdx.x;
  const int tid = threadIdx.x;
  __shared__ int sJ[CAP];
  __shared__ float sW[CAP];
  const int c = min(cnt[i], CAP);
  if (tid < c) {
    const int j = nbrJ[(size_t)i * CAP + tid];
    sJ[tid] = j;
    sW[tid] = nbrW[(size_t)i * CAP + tid] * Dv[j];
  }
  __syncthreads();
  float acc = 0.f;
  for (int m = 0; m < c; ++m) acc += sW[m] * Psi[(size_t)sJ[m] * K_EIG + tid];
  gP[(size_t)i * K_EIG + tid] = acc * Dv[i];
}

// ---------- kernel 7: R = s^2 * Psi^T @ gPsi  (256x256) ----------
__global__ __launch_bounds__(256) void k_R(const float* __restrict__ Psi,
                                           const float* __restrict__ gP,
                                           float* __restrict__ Rm) {
  __shared__ float sP[128][32];
  __shared__ float sG[128][32];
  const int tid = threadIdx.x;
  const int at = (blockIdx.x >> 3) * 32;
  const int bt = (blockIdx.x & 7) * 32;
  const int a = tid & 31;
  const int bg = tid >> 5;
  float acc[4] = {0.f, 0.f, 0.f, 0.f};
  for (int nt = 0; nt < N_TOK / 128; ++nt) {
    __syncthreads();
    for (int idx = tid; idx < 128 * 32; idx += 256) {
      const int r = idx >> 5, cc = idx & 31;
      sP[r][cc] = Psi[(size_t)(nt * 128 + r) * K_EIG + at + cc];
      sG[r][cc] = gP[(size_t)(nt * 128 + r) * K_EIG + bt + cc];
    }
    __syncthreads();
#pragma unroll 4
    for (int r = 0; r < 128; ++r) {
      const float va = sP[r][a];
      const float4 g = *(const float4*)&sG[r][bg * 4];
      acc[0] += va * g.x; acc[1] += va * g.y; acc[2] += va * g.z; acc[3] += va * g.w;
    }
  }
  const float s2 = (10.f / 8192.f) * (10.f / 8192.f);
#pragma unroll
  for (int jj = 0; jj < 4; ++jj)
    Rm[(size_t)(at + a) * K_EIG + bt + bg * 4 + jj] = acc[jj] * s2;
}

// ---------- kernel 8: loss = -trace(R); reg = alpha * sum(triu(R^2,1)) ----------
__global__ void k_final(const float* __restrict__ Rm, float* __restrict__ out) {
  __shared__ double st[256];
  __shared__ double sr[256];
  const int tid = threadIdx.x;
  double tl = 0.0, rg = 0.0;
  for (int i = tid; i < K_EIG * K_EIG; i += 256) {
    const int a = i >> 8, b = i & 255;
    const double v = (double)Rm[i];
    if (a == b) tl += v;
    else if (b > a) rg += v * v;
  }
  st[tid] = tl; sr[tid] = rg;
  __syncthreads();
  for (int s = 128; s > 0; s >>= 1) {
    if (tid < s) { st[tid] += st[tid + s]; sr[tid] += sr[tid + s]; }
    __syncthreads();
  }
  if (tid == 0) {
    out[0] = (float)(-st[0]);
    out[1] = (float)(sr[0] * 0.05);
  }
}

extern "C" void kernel_launch(void* const* d_in, const int* in_sizes, int n_in,
                              void* d_out, int out_size, void* d_ws, size_t ws_size,
                              hipStream_t stream) {
  const float* FF = (const float*)d_in[0];
  const float* Psi = (const float*)d_in[1];
  float* out = (float*)d_out;
  float* ws = (float*)d_ws;

  size_t o = 0;
  float* FFn = ws + o; o += (size_t)N_TOK * D_FEAT;
  float* sqv = ws + o; o += N_TOK;
  float* pd  = ws + o; o += (size_t)N_TOK * NCHUNK * KNN;
  int*   pi  = (int*)(ws + o); o += (size_t)N_TOK * NCHUNK * KNN;
  float* tv  = ws + o; o += (size_t)N_TOK * KNN;
  int*   tj  = (int*)(ws + o); o += (size_t)N_TOK * KNN;
  int*   cnt = (int*)(ws + o); o += N_TOK;
  int*   nbrJ = (int*)(ws + o); o += (size_t)N_TOK * CAP;
  float* nbrW = ws + o; o += (size_t)N_TOK * CAP;
  float* Dv  = ws + o; o += N_TOK;
  float* gP  = ws + o; o += (size_t)N_TOK * K_EIG;
  float* Rm  = ws + o; o += (size_t)K_EIG * K_EIG;

  k_norm<<<N_TOK, 256, 0, stream>>>(FF, FFn, sqv);
  k_gram_topk<<<(N_TOK / ROWS_PB) * NCHUNK, 256, 0, stream>>>(FFn, pd, pi);
  k_mergefinal<<<N_TOK / 256, 256, 0, stream>>>(pd, pi, sqv, tv, tj);
  hipMemsetAsync(cnt, 0, N_TOK * sizeof(int), stream);
  k_scatter<<<(N_TOK * KNN + 255) / 256, 256, 0, stream>>>(tv, tj, cnt, nbrJ, nbrW);
  k_degree<<<N_TOK / 4, 256, 0, stream>>>(cnt, nbrW, Dv);
  k_gpsi<<<N_TOK, 256, 0, stream>>>(Psi, cnt, nbrJ, nbrW, Dv, gP);
  k_R<<<64, 256, 0, stream>>>(Psi, gP, Rm);
  k_final<<<1, 256, 0, stream>>>(Rm, out);
}

// Round 2
// 2702.800 us; speedup vs baseline: 1.2946x; 1.2946x over previous
//
#include <hip/hip_runtime.h>
#include <math.h>

#define N_TOK 8192
#define D_FEAT 768
#define K_EIG 256
#define KNN 10
#define CAP 256
#define NCHUNK 4
#define CHUNK 2048

typedef unsigned short ushort_t;
typedef float f32x4 __attribute__((ext_vector_type(4)));
typedef short bf16x8 __attribute__((ext_vector_type(8)));
typedef unsigned short u16x8 __attribute__((ext_vector_type(8)));

__device__ inline float u2f(unsigned u) { union { unsigned u; float f; } c; c.u = u; return c.f; }
__device__ inline unsigned f2u(float f) { union { unsigned u; float f; } c; c.f = f; return c.u; }
__device__ inline ushort_t f2bf_rne(float f) {
  const unsigned u = f2u(f);
  return (ushort_t)((u + 0x7fffu + ((u >> 16) & 1u)) >> 16);
}

// sorted-descending insertion with early-out
template <int K>
__device__ inline void insertK(float (&v)[K], int (&ix)[K], float nv, int ni) {
  if (nv <= v[K - 1]) return;
  bool carry = false;
#pragma unroll
  for (int s = 0; s < K; ++s) {
    const bool doSwap = carry || (nv > v[s]);
    if (doSwap) {
      const float tvv = v[s]; const int tii = ix[s];
      v[s] = nv; ix[s] = ni;
      nv = tvv; ni = tii;
      carry = true;
    }
  }
}

// ---------- kernel 1: row stats + bf16 normalized copy ----------
__global__ __launch_bounds__(256) void k_norm(const float* __restrict__ FF,
                                              ushort_t* __restrict__ FFbf,
                                              float* __restrict__ rn,
                                              float* __restrict__ sqv) {
  const int row = blockIdx.x;
  const int tid = threadIdx.x;
  const float* src = FF + (size_t)row * D_FEAT;
  float s = 0.f;
  for (int i = tid; i < D_FEAT; i += 256) { const float v = src[i]; s += v * v; }
  __shared__ float red[4];
  for (int m = 32; m > 0; m >>= 1) s += __shfl_xor(s, m, 64);
  if ((tid & 63) == 0) red[tid >> 6] = s;
  __syncthreads();
  const float tot = red[0] + red[1] + red[2] + red[3];
  const float scale = 1.f / fmaxf(sqrtf(tot), 1e-12f);
  float s2 = 0.f;
  ushort_t* dst = FFbf + (size_t)row * D_FEAT;
  for (int i = tid; i < D_FEAT; i += 256) {
    const float v = src[i] * scale;
    s2 += v * v;
    dst[i] = f2bf_rne(v);
  }
  for (int m = 32; m > 0; m >>= 1) s2 += __shfl_xor(s2, m, 64);
  __syncthreads();
  if ((tid & 63) == 0) red[tid >> 6] = s2;
  __syncthreads();
  if (tid == 0) { sqv[row] = red[0] + red[1] + red[2] + red[3]; rn[row] = scale; }
}

// ---------- kernel 2: bf16 MFMA GEMM chunk: Cs[8192][2048] = FFbf @ FFbf^T ----------
#define AS1(p) ((const __attribute__((address_space(1))) void*)(p))
#define AS3(p) ((__attribute__((address_space(3))) void*)(p))

__global__ __launch_bounds__(256) void k_gemm(const ushort_t* __restrict__ FFbf,
                                              ushort_t* __restrict__ Cs,
                                              int cbase) {
  __shared__ ushort_t As[2][128 * 32];
  __shared__ ushort_t Bs[2][128 * 32];
  const int tid = threadIdx.x;
  const int mb = blockIdx.x & 63;
  const int nb = blockIdx.x >> 6;
  const int rbase = mb * 128;
  const int cb = cbase + nb * 128;   // global row index of this col-tile
  const int w = tid >> 6, lane = tid & 63;
  const int wr = w >> 1, wc = w & 1;
  const int fr = lane & 15;
  const int kg = lane >> 4;
  const int srow = tid >> 2, skq = tid & 3;

  f32x4 acc[4][4];
#pragma unroll
  for (int m = 0; m < 4; ++m)
#pragma unroll
    for (int n = 0; n < 4; ++n) acc[m][n] = (f32x4){0.f, 0.f, 0.f, 0.f};

#define STAGE(b, kt) do { \
    const ushort_t* ga = FFbf + (size_t)(rbase + srow) * D_FEAT + (kt) * 32 + skq * 8; \
    const ushort_t* gb = FFbf + (size_t)(cb + srow) * D_FEAT + (kt) * 32 + skq * 8; \
    __builtin_amdgcn_global_load_lds(AS1(ga), AS3((char*)&As[b][0] + tid * 16), 16, 0, 0); \
    __builtin_amdgcn_global_load_lds(AS1(gb), AS3((char*)&Bs[b][0] + tid * 16), 16, 0, 0); \
    __builtin_amdgcn_global_load_lds(AS1(ga + (size_t)64 * D_FEAT), AS3((char*)&As[b][0] + 4096 + tid * 16), 16, 0, 0); \
    __builtin_amdgcn_global_load_lds(AS1(gb + (size_t)64 * D_FEAT), AS3((char*)&Bs[b][0] + 4096 + tid * 16), 16, 0, 0); \
  } while (0)

  STAGE(0, 0);
  int buf = 0;
  for (int kt = 0; kt < D_FEAT / 32; ++kt) {
    __syncthreads();
    if (kt + 1 < D_FEAT / 32) STAGE(buf ^ 1, kt + 1);
    bf16x8 af[4], bfr[4];
#pragma unroll
    for (int m = 0; m < 4; ++m)
      af[m] = *(const bf16x8*)&As[buf][(wr * 64 + m * 16 + fr) * 32 + kg * 8];
#pragma unroll
    for (int n = 0; n < 4; ++n)
      bfr[n] = *(const bf16x8*)&Bs[buf][(wc * 64 + n * 16 + fr) * 32 + kg * 8];
#pragma unroll
    for (int m = 0; m < 4; ++m)
#pragma unroll
      for (int n = 0; n < 4; ++n)
        acc[m][n] = __builtin_amdgcn_mfma_f32_16x16x32_bf16(af[m], bfr[n], acc[m][n], 0, 0, 0);
    buf ^= 1;
  }
#undef STAGE

  // epilogue: C/D layout col = lane&15, row = (lane>>4)*4 + reg  [guide m89]
#pragma unroll
  for (int m = 0; m < 4; ++m) {
#pragma unroll
    for (int n = 0; n < 4; ++n) {
      const int colc = nb * 128 + wc * 64 + n * 16 + fr;
      const int row0 = rbase + wr * 64 + m * 16 + kg * 4;
#pragma unroll
      for (int r = 0; r < 4; ++r) {
        // truncation is monotone -> fine for ranking
        Cs[(size_t)(row0 + r) * CHUNK + colc] = (ushort_t)(f2u(acc[m][n][r]) >> 16);
      }
    }
  }
}

// ---------- kernel 3: per-chunk top-16 (bf16 ranks) ----------
__global__ __launch_bounds__(256) void k_top16(const ushort_t* __restrict__ Cs, int chunk,
                                               float* __restrict__ pd, int* __restrict__ pi) {
  __shared__ float sv[16 * 256];
  __shared__ int si[16 * 256];
  const int tid = threadIdx.x;
  const int rloc = tid >> 4, p = tid & 15;
  const int row = blockIdx.x * 16 + rloc;
  float v[16]; int ix[16];
#pragma unroll
  for (int s = 0; s < 16; ++s) { v[s] = -1e30f; ix[s] = 0; }
  const ushort_t* src = Cs + (size_t)row * CHUNK;
  for (int q = 0; q < 16; ++q) {
    const int c0 = (q * 16 + p) * 8;
    const u16x8 u = *(const u16x8*)&src[c0];
#pragma unroll
    for (int j = 0; j < 8; ++j) {
      const float f = u2f(((unsigned)(ushort_t)u[j]) << 16);
      insertK<16>(v, ix, f, chunk * CHUNK + c0 + j);
    }
  }
#pragma unroll
  for (int s = 0; s < 16; ++s) { sv[rloc * 256 + p * 16 + s] = v[s]; si[rloc * 256 + p * 16 + s] = ix[s]; }
  __syncthreads();
  if (p == 0) {
    for (int e = 16; e < 256; ++e) insertK<16>(v, ix, sv[rloc * 256 + e], si[rloc * 256 + e]);
#pragma unroll
    for (int s = 0; s < 16; ++s) {
      pd[((size_t)row * NCHUNK + chunk) * 16 + s] = v[s];
      pi[((size_t)row * NCHUNK + chunk) * 16 + s] = ix[s];
    }
  }
}

// ---------- kernel 4: exact fp32 rescore of 16 merged candidates -> top-10 + exp ----------
__global__ __launch_bounds__(256) void k_rescore(const float* __restrict__ FF,
                                                 const float* __restrict__ rn,
                                                 const float* __restrict__ sqv,
                                                 const float* __restrict__ pd,
                                                 const int* __restrict__ pi,
                                                 float* __restrict__ tv, int* __restrict__ tj) {
  const int row = blockIdx.x, tid = threadIdx.x;
  __shared__ int selj[16];
  __shared__ float dsc[16], dvl[16];
  __shared__ int djx[16];
  if (tid == 0) {
    float v[16]; int ix[16];
#pragma unroll
    for (int s = 0; s < 16; ++s) { v[s] = -1e30f; ix[s] = 0; }
    for (int e = 0; e < NCHUNK * 16; ++e)
      insertK<16>(v, ix, pd[(size_t)row * NCHUNK * 16 + e], pi[(size_t)row * NCHUNK * 16 + e]);
#pragma unroll
    for (int s = 0; s < 16; ++s) selj[s] = ix[s];
  }
  __syncthreads();
  const int c = tid >> 4, ln = tid & 15;
  const int j = selj[c];
  const float si = rn[row], sj = rn[j];
  const float* fi = FF + (size_t)row * D_FEAT;
  const float* fj = FF + (size_t)j * D_FEAT;
  float acc = 0.f;
#pragma unroll
  for (int t = 0; t < 12; ++t) {
    const float4 a = *(const float4*)&fi[t * 64 + ln * 4];
    const float4 b = *(const float4*)&fj[t * 64 + ln * 4];
    acc = fmaf(a.x * si, b.x * sj, acc);
    acc = fmaf(a.y * si, b.y * sj, acc);
    acc = fmaf(a.z * si, b.z * sj, acc);
    acc = fmaf(a.w * si, b.w * sj, acc);
  }
  for (int m = 8; m > 0; m >>= 1) acc += __shfl_xor(acc, m, 64);
  if (ln == 0) {
    const float d = acc;
    const float sqj = sqv[j];
    dsc[c] = d - 0.5f * sqj;                                   // exactly monotone with exp comparator
    dvl[c] = expf(-0.5f * (sqv[row] + sqj - 2.f * d));
    djx[c] = j;
  }
  __syncthreads();
  if (tid == 0) {
    float v[10]; int ix[10];
#pragma unroll
    for (int s = 0; s < 10; ++s) { v[s] = -1e30f; ix[s] = 0; }
    for (int c2 = 0; c2 < 16; ++c2) insertK<10>(v, ix, dsc[c2], c2);
#pragma unroll
    for (int s = 0; s < 10; ++s) {
      tv[(size_t)row * KNN + s] = dvl[ix[s]];
      tj[(size_t)row * KNN + s] = djx[ix[s]];
    }
  }
}

// ---------- kernel 5: scatter both edge directions ----------
__global__ void k_scatter(const float* __restrict__ tv, const int* __restrict__ tj,
                          int* __restrict__ cnt, int* __restrict__ nbrJ,
                          float* __restrict__ nbrW) {
  const int e = blockIdx.x * blockDim.x + threadIdx.x;
  if (e >= N_TOK * KNN) return;
  const int i = e / KNN;
  const int j = tj[e];
  if (j == i) return;
  const float w = 0.5f * tv[e];
  const int p = atomicAdd(&cnt[i], 1);
  if (p < CAP) { nbrJ[(size_t)i * CAP + p] = j; nbrW[(size_t)i * CAP + p] = w; }
  const int q = atomicAdd(&cnt[j], 1);
  if (q < CAP) { nbrJ[(size_t)j * CAP + q] = i; nbrW[(size_t)j * CAP + q] = w; }
}

// ---------- kernel 6: degree + rsqrt ----------
__global__ void k_degree(const int* __restrict__ cnt, const float* __restrict__ nbrW,
                         float* __restrict__ Dv) {
  const int r = blockIdx.x * 4 + (threadIdx.x >> 6);
  const int lane = threadIdx.x & 63;
  const int c = min(cnt[r], CAP);
  float s = 0.f;
  for (int m = lane; m < c; m += 64) s += nbrW[(size_t)r * CAP + m];
  for (int m = 32; m > 0; m >>= 1) s += __shfl_xor(s, m, 64);
  if (lane == 0) Dv[r] = (s > 0.f) ? rsqrtf(s) : 0.f;
}

// ---------- kernel 7: gPsi ----------
__global__ __launch_bounds__(256) void k_gpsi(const float* __restrict__ Psi,
                                              const int* __restrict__ cnt,
                                              const int* __restrict__ nbrJ,
                                              const float* __restrict__ nbrW,
                                              const float* __restrict__ Dv,
                                              float* __restrict__ gP) {
  const int i = blockIdx.x;
  const int tid = threadIdx.x;
  __shared__ int sJ[CAP];
  __shared__ float sW[CAP];
  const int c = min(cnt[i], CAP);
  if (tid < c) {
    const int j = nbrJ[(size_t)i * CAP + tid];
    sJ[tid] = j;
    sW[tid] = nbrW[(size_t)i * CAP + tid] * Dv[j];
  }
  __syncthreads();
  float acc = 0.f;
  for (int m = 0; m < c; ++m) acc += sW[m] * Psi[(size_t)sJ[m] * K_EIG + tid];
  gP[(size_t)i * K_EIG + tid] = acc * Dv[i];
}

// ---------- kernel 8: R = s^2 * Psi^T @ gPsi ----------
__global__ __launch_bounds__(256) void k_R(const float* __restrict__ Psi,
                                           const float* __restrict__ gP,
                                           float* __restrict__ Rm) {
  __shared__ float sP[128][32];
  __shared__ float sG[128][32];
  const int tid = threadIdx.x;
  const int at = (blockIdx.x >> 3) * 32;
  const int bt = (blockIdx.x & 7) * 32;
  const int a = tid & 31;
  const int bg = tid >> 5;
  float acc[4] = {0.f, 0.f, 0.f, 0.f};
  for (int nt = 0; nt < N_TOK / 128; ++nt) {
    __syncthreads();
    for (int idx = tid; idx < 128 * 32; idx += 256) {
      const int r = idx >> 5, cc = idx & 31;
      sP[r][cc] = Psi[(size_t)(nt * 128 + r) * K_EIG + at + cc];
      sG[r][cc] = gP[(size_t)(nt * 128 + r) * K_EIG + bt + cc];
    }
    __syncthreads();
#pragma unroll 4
    for (int r = 0; r < 128; ++r) {
      const float va = sP[r][a];
      const float4 g = *(const float4*)&sG[r][bg * 4];
      acc[0] += va * g.x; acc[1] += va * g.y; acc[2] += va * g.z; acc[3] += va * g.w;
    }
  }
  const float s2 = (10.f / 8192.f) * (10.f / 8192.f);
#pragma unroll
  for (int jj = 0; jj < 4; ++jj)
    Rm[(size_t)(at + a) * K_EIG + bt + bg * 4 + jj] = acc[jj] * s2;
}

// ---------- kernel 9: final scalars ----------
__global__ void k_final(const float* __restrict__ Rm, float* __restrict__ out) {
  __shared__ double st[256];
  __shared__ double sr[256];
  const int tid = threadIdx.x;
  double tl = 0.0, rg = 0.0;
  for (int i = tid; i < K_EIG * K_EIG; i += 256) {
    const int a = i >> 8, b = i & 255;
    const double v = (double)Rm[i];
    if (a == b) tl += v;
    else if (b > a) rg += v * v;
  }
  st[tid] = tl; sr[tid] = rg;
  __syncthreads();
  for (int s = 128; s > 0; s >>= 1) {
    if (tid < s) { st[tid] += st[tid + s]; sr[tid] += sr[tid + s]; }
    __syncthreads();
  }
  if (tid == 0) {
    out[0] = (float)(-st[0]);
    out[1] = (float)(sr[0] * 0.05);
  }
}

extern "C" void kernel_launch(void* const* d_in, const int* in_sizes, int n_in,
                              void* d_out, int out_size, void* d_ws, size_t ws_size,
                              hipStream_t stream) {
  const float* FF = (const float*)d_in[0];
  const float* Psi = (const float*)d_in[1];
  float* out = (float*)d_out;
  float* ws = (float*)d_ws;

  size_t o = 0;
  ushort_t* FFbf = (ushort_t*)(ws + o); o += (size_t)N_TOK * D_FEAT / 2;
  float* rn  = ws + o; o += N_TOK;
  float* sqv = ws + o; o += N_TOK;
  float* pd  = ws + o; o += (size_t)N_TOK * NCHUNK * 16;
  int*   pi  = (int*)(ws + o); o += (size_t)N_TOK * NCHUNK * 16;
  float* tv  = ws + o; o += (size_t)N_TOK * KNN;
  int*   tj  = (int*)(ws + o); o += (size_t)N_TOK * KNN;
  int*   cnt = (int*)(ws + o); o += N_TOK;
  float* Rm  = ws + o; o += (size_t)K_EIG * K_EIG;
  // region X: Cs (33.5 MB) aliased with {nbrJ, nbrW, Dv, gP} (25.2 MB) — Cs dead after k_rescore
  char* X = (char*)(ws + o);
  ushort_t* Cs = (ushort_t*)X;
  int*   nbrJ = (int*)X;
  float* nbrW = (float*)(X + (size_t)N_TOK * CAP * 4);
  float* Dv   = (float*)(X + 2 * (size_t)N_TOK * CAP * 4);
  float* gP   = (float*)(X + 2 * (size_t)N_TOK * CAP * 4 + (size_t)N_TOK * 4);

  k_norm<<<N_TOK, 256, 0, stream>>>(FF, FFbf, rn, sqv);
  for (int c = 0; c < NCHUNK; ++c) {
    k_gemm<<<(N_TOK / 128) * (CHUNK / 128), 256, 0, stream>>>(FFbf, Cs, c * CHUNK);
    k_top16<<<N_TOK / 16, 256, 0, stream>>>(Cs, c, pd, pi);
  }
  k_rescore<<<N_TOK, 256, 0, stream>>>(FF, rn, sqv, pd, pi, tv, tj);
  hipMemsetAsync(cnt, 0, N_TOK * sizeof(int), stream);
  k_scatter<<<(N_TOK * KNN + 255) / 256, 256, 0, stream>>>(tv, tj, cnt, nbrJ, nbrW);
  k_degree<<<N_TOK / 4, 256, 0, stream>>>(cnt, nbrW, Dv);
  k_gpsi<<<N_TOK, 256, 0, stream>>>(Psi, cnt, nbrJ, nbrW, Dv, gP);
  k_R<<<64, 256, 0, stream>>>(Psi, gP, Rm);
  k_final<<<1, 256, 0, stream>>>(Rm, out);
}

// Round 3
// 872.871 us; speedup vs baseline: 4.0086x; 3.0964x over previous
//
#include <hip/hip_runtime.h>
#include <math.h>

#define N_TOK 8192
#define D_FEAT 768
#define K_EIG 256
#define KNN 10
#define CAP 256
#define NCHUNK 4
#define CHUNK 2048

typedef unsigned short ushort_t;
typedef float f32x4 __attribute__((ext_vector_type(4)));
typedef short bf16x8 __attribute__((ext_vector_type(8)));
typedef unsigned short u16x8 __attribute__((ext_vector_type(8)));

__device__ inline float u2f(unsigned u) { union { unsigned u; float f; } c; c.u = u; return c.f; }
__device__ inline unsigned f2u(float f) { union { unsigned u; float f; } c; c.f = f; return c.u; }
__device__ inline ushort_t f2bf_rne(float f) {
  const unsigned u = f2u(f);
  return (ushort_t)((u + 0x7fffu + ((u >> 16) & 1u)) >> 16);
}
// monotone u16 key from f32 (truncate to bf16, flip for total order)
__device__ inline ushort_t f2key(float f) {
  const unsigned h = f2u(f) >> 16;
  return (ushort_t)((h & 0x8000u) ? (h ^ 0xFFFFu) : (h | 0x8000u));
}
__device__ inline float key2f(unsigned k) {
  const unsigned h = (k & 0x8000u) ? (k ^ 0x8000u) : (k ^ 0xFFFFu);
  return u2f(h << 16);
}

// sorted-descending insertion with early-out (used in small merges only)
template <int K>
__device__ inline void insertK(float (&v)[K], int (&ix)[K], float nv, int ni) {
  if (nv <= v[K - 1]) return;
  bool carry = false;
#pragma unroll
  for (int s = 0; s < K; ++s) {
    const bool doSwap = carry || (nv > v[s]);
    if (doSwap) {
      const float tvv = v[s]; const int tii = ix[s];
      v[s] = nv; ix[s] = ni;
      nv = tvv; ni = tii;
      carry = true;
    }
  }
}

// ---------- kernel 1: row stats + bf16 normalized copy ----------
__global__ __launch_bounds__(256) void k_norm(const float* __restrict__ FF,
                                              ushort_t* __restrict__ FFbf,
                                              float* __restrict__ rn,
                                              float* __restrict__ sqv) {
  const int row = blockIdx.x;
  const int tid = threadIdx.x;
  const float* src = FF + (size_t)row * D_FEAT;
  float s = 0.f;
  for (int i = tid; i < D_FEAT; i += 256) { const float v = src[i]; s += v * v; }
  __shared__ float red[4];
  for (int m = 32; m > 0; m >>= 1) s += __shfl_xor(s, m, 64);
  if ((tid & 63) == 0) red[tid >> 6] = s;
  __syncthreads();
  const float tot = red[0] + red[1] + red[2] + red[3];
  const float scale = 1.f / fmaxf(sqrtf(tot), 1e-12f);
  float s2 = 0.f;
  ushort_t* dst = FFbf + (size_t)row * D_FEAT;
  for (int i = tid; i < D_FEAT; i += 256) {
    const float v = src[i] * scale;
    s2 += v * v;
    dst[i] = f2bf_rne(v);
  }
  for (int m = 32; m > 0; m >>= 1) s2 += __shfl_xor(s2, m, 64);
  __syncthreads();
  if ((tid & 63) == 0) red[tid >> 6] = s2;
  __syncthreads();
  if (tid == 0) { sqv[row] = red[0] + red[1] + red[2] + red[3]; rn[row] = scale; }
}

// ---------- kernel 2: bf16 MFMA GEMM chunk -> u16 keys, LDS-transposed store ----------
#define AS1(p) ((const __attribute__((address_space(1))) void*)(p))
#define AS3(p) ((__attribute__((address_space(3))) void*)(p))

__global__ __launch_bounds__(256) void k_gemm(const ushort_t* __restrict__ FFbf,
                                              ushort_t* __restrict__ Cs,
                                              int cbase) {
  __shared__ ushort_t smem[16384];  // 32KB: staging (2buf A + 2buf B) then C-tile
  const int tid = threadIdx.x;
  const int mb = blockIdx.x & 63;
  const int nb = blockIdx.x >> 6;
  const int rbase = mb * 128;
  const int cb = cbase + nb * 128;
  const int w = tid >> 6, lane = tid & 63;
  const int wr = w >> 1, wc = w & 1;
  const int fr = lane & 15;
  const int kg = lane >> 4;
  const int srow = tid >> 2, skq = tid & 3;

  f32x4 acc[4][4];
#pragma unroll
  for (int m = 0; m < 4; ++m)
#pragma unroll
    for (int n = 0; n < 4; ++n) acc[m][n] = (f32x4){0.f, 0.f, 0.f, 0.f};

#define STAGE(b, kt) do { \
    const ushort_t* ga = FFbf + (size_t)(rbase + srow) * D_FEAT + (kt) * 32 + skq * 8; \
    const ushort_t* gb = FFbf + (size_t)(cb + srow) * D_FEAT + (kt) * 32 + skq * 8; \
    char* abase = (char*)&smem[(b) * 4096]; \
    char* bbase = (char*)&smem[8192 + (b) * 4096]; \
    __builtin_amdgcn_global_load_lds(AS1(ga), AS3(abase + tid * 16), 16, 0, 0); \
    __builtin_amdgcn_global_load_lds(AS1(gb), AS3(bbase + tid * 16), 16, 0, 0); \
    __builtin_amdgcn_global_load_lds(AS1(ga + (size_t)64 * D_FEAT), AS3(abase + 4096 + tid * 16), 16, 0, 0); \
    __builtin_amdgcn_global_load_lds(AS1(gb + (size_t)64 * D_FEAT), AS3(bbase + 4096 + tid * 16), 16, 0, 0); \
  } while (0)

  STAGE(0, 0);
  int buf = 0;
  for (int kt = 0; kt < D_FEAT / 32; ++kt) {
    __syncthreads();
    if (kt + 1 < D_FEAT / 32) STAGE(buf ^ 1, kt + 1);
    bf16x8 af[4], bfr[4];
#pragma unroll
    for (int m = 0; m < 4; ++m)
      af[m] = *(const bf16x8*)&smem[buf * 4096 + (wr * 64 + m * 16 + fr) * 32 + kg * 8];
#pragma unroll
    for (int n = 0; n < 4; ++n)
      bfr[n] = *(const bf16x8*)&smem[8192 + buf * 4096 + (wc * 64 + n * 16 + fr) * 32 + kg * 8];
#pragma unroll
    for (int m = 0; m < 4; ++m)
#pragma unroll
      for (int n = 0; n < 4; ++n)
        acc[m][n] = __builtin_amdgcn_mfma_f32_16x16x32_bf16(af[m], bfr[n], acc[m][n], 0, 0, 0);
    buf ^= 1;
  }
#undef STAGE

  // epilogue: keys -> LDS [128][128] u16 -> coalesced 16B global stores
  __syncthreads();
#pragma unroll
  for (int m = 0; m < 4; ++m)
#pragma unroll
    for (int n = 0; n < 4; ++n)
#pragma unroll
      for (int r = 0; r < 4; ++r)
        smem[(wr * 64 + m * 16 + kg * 4 + r) * 128 + wc * 64 + n * 16 + fr] = f2key(acc[m][n][r]);
  __syncthreads();
#pragma unroll
  for (int i = 0; i < 8; ++i) {
    const int off = i * 4096 + tid * 16;       // byte offset in 32KB tile
    const int row = off >> 8;                  // 256B per tile row
    const int colb = off & 255;
    const u16x8 v = *(const u16x8*)((const char*)smem + off);
    *(u16x8*)((char*)Cs + (size_t)(rbase + row) * (CHUNK * 2) + (size_t)nb * 256 + colb) = v;
  }
}

// ---------- kernel 3: exact per-row top-16 via group-max + wave extract ----------
__global__ __launch_bounds__(256) void k_sel(const ushort_t* __restrict__ Cs, int chunk,
                                             float* __restrict__ pd, int* __restrict__ pi) {
  const int tid = threadIdx.x;
  const int lane = tid & 63;
  const int row = blockIdx.x * 4 + (tid >> 6);
  const ushort_t* src = Cs + (size_t)row * CHUNK;

  // phase 0: group-of-8 maxes (256 groups; group g = cols [g*8, g*8+8))
  unsigned G[4];
#pragma unroll
  for (int t = 0; t < 4; ++t) {
    const u16x8 raw = *(const u16x8*)&src[t * 512 + lane * 8];
    unsigned m = 0;
#pragma unroll
    for (int j = 0; j < 8; ++j) m = max(m, (unsigned)(ushort_t)raw[j]);
    G[t] = (m << 16) | (unsigned)(t * 64 + lane);
  }
  // phase 1: extract top-16 groups (branchless wave max-extract)
  unsigned keep = 0;
#pragma unroll
  for (int r = 0; r < 16; ++r) {
    unsigned m = max(max(G[0], G[1]), max(G[2], G[3]));
#pragma unroll
    for (int s = 1; s < 64; s <<= 1) m = max(m, (unsigned)__shfl_xor((int)m, s, 64));
    if (lane == r) keep = m;
    const unsigned gid = m & 0xFFu;
    const int ow = (int)(gid & 63u), sl = (int)(gid >> 6);
#pragma unroll
    for (int t = 0; t < 4; ++t)
      if (lane == ow && t == sl) G[t] = 0;
  }
  // phase 2: gather 16 winning groups (128 elems), extract exact top-16
  const unsigned gid2 = keep & 0xFFu;  // valid for lanes 0..15
  unsigned E[8];
  if (lane < 16) {
    const u16x8 g = *(const u16x8*)&src[gid2 * 8];
#pragma unroll
    for (int j = 0; j < 8; ++j)
      E[j] = (((unsigned)(ushort_t)g[j]) << 16) | (gid2 * 8 + (unsigned)j);
  } else {
#pragma unroll
    for (int j = 0; j < 8; ++j) E[j] = 0;
  }
  unsigned keep2 = 0;
#pragma unroll
  for (int r = 0; r < 16; ++r) {
    unsigned m = E[0];
#pragma unroll
    for (int j = 1; j < 8; ++j) m = max(m, E[j]);
#pragma unroll
    for (int s = 1; s < 64; s <<= 1) m = max(m, (unsigned)__shfl_xor((int)m, s, 64));
    if (lane == r) keep2 = m;
    const unsigned col = m & 0xFFFFu;
    const bool mine = (lane < 16) && ((col >> 3) == gid2);
    const int sl = (int)(col & 7u);
#pragma unroll
    for (int j = 0; j < 8; ++j)
      if (mine && j == sl) E[j] = 0;
  }
  if (lane < 16) {
    pd[((size_t)row * NCHUNK + chunk) * 16 + lane] = key2f(keep2 >> 16);
    pi[((size_t)row * NCHUNK + chunk) * 16 + lane] = chunk * CHUNK + (int)(keep2 & 0xFFFFu);
  }
}

// ---------- kernel 4: exact fp32 rescore of 16 merged candidates -> top-10 + exp ----------
__global__ __launch_bounds__(256) void k_rescore(const float* __restrict__ FF,
                                                 const float* __restrict__ rn,
                                                 const float* __restrict__ sqv,
                                                 const float* __restrict__ pd,
                                                 const int* __restrict__ pi,
                                                 float* __restrict__ tv, int* __restrict__ tj) {
  const int row = blockIdx.x, tid = threadIdx.x;
  __shared__ int selj[16];
  __shared__ float dsc[16], dvl[16];
  __shared__ int djx[16];
  if (tid == 0) {
    float v[16]; int ix[16];
#pragma unroll
    for (int s = 0; s < 16; ++s) { v[s] = -1e30f; ix[s] = 0; }
    for (int e = 0; e < NCHUNK * 16; ++e)
      insertK<16>(v, ix, pd[(size_t)row * NCHUNK * 16 + e], pi[(size_t)row * NCHUNK * 16 + e]);
#pragma unroll
    for (int s = 0; s < 16; ++s) selj[s] = ix[s];
  }
  __syncthreads();
  const int c = tid >> 4, ln = tid & 15;
  const int j = selj[c];
  const float si = rn[row], sj = rn[j];
  const float* fi = FF + (size_t)row * D_FEAT;
  const float* fj = FF + (size_t)j * D_FEAT;
  float acc = 0.f;
#pragma unroll
  for (int t = 0; t < 12; ++t) {
    const float4 a = *(const float4*)&fi[t * 64 + ln * 4];
    const float4 b = *(const float4*)&fj[t * 64 + ln * 4];
    acc = fmaf(a.x * si, b.x * sj, acc);
    acc = fmaf(a.y * si, b.y * sj, acc);
    acc = fmaf(a.z * si, b.z * sj, acc);
    acc = fmaf(a.w * si, b.w * sj, acc);
  }
  for (int m = 8; m > 0; m >>= 1) acc += __shfl_xor(acc, m, 64);
  if (ln == 0) {
    const float d = acc;
    const float sqj = sqv[j];
    dsc[c] = d - 0.5f * sqj;
    dvl[c] = expf(-0.5f * (sqv[row] + sqj - 2.f * d));
    djx[c] = j;
  }
  __syncthreads();
  if (tid == 0) {
    float v[10]; int ix[10];
#pragma unroll
    for (int s = 0; s < 10; ++s) { v[s] = -1e30f; ix[s] = 0; }
    for (int c2 = 0; c2 < 16; ++c2) insertK<10>(v, ix, dsc[c2], c2);
#pragma unroll
    for (int s = 0; s < 10; ++s) {
      tv[(size_t)row * KNN + s] = dvl[ix[s]];
      tj[(size_t)row * KNN + s] = djx[ix[s]];
    }
  }
}

// ---------- kernel 5: scatter both edge directions ----------
__global__ void k_scatter(const float* __restrict__ tv, const int* __restrict__ tj,
                          int* __restrict__ cnt, int* __restrict__ nbrJ,
                          float* __restrict__ nbrW) {
  const int e = blockIdx.x * blockDim.x + threadIdx.x;
  if (e >= N_TOK * KNN) return;
  const int i = e / KNN;
  const int j = tj[e];
  if (j == i) return;
  const float w = 0.5f * tv[e];
  const int p = atomicAdd(&cnt[i], 1);
  if (p < CAP) { nbrJ[(size_t)i * CAP + p] = j; nbrW[(size_t)i * CAP + p] = w; }
  const int q = atomicAdd(&cnt[j], 1);
  if (q < CAP) { nbrJ[(size_t)j * CAP + q] = i; nbrW[(size_t)j * CAP + q] = w; }
}

// ---------- kernel 6: degree + rsqrt ----------
__global__ void k_degree(const int* __restrict__ cnt, const float* __restrict__ nbrW,
                         float* __restrict__ Dv) {
  const int r = blockIdx.x * 4 + (threadIdx.x >> 6);
  const int lane = threadIdx.x & 63;
  const int c = min(cnt[r], CAP);
  float s = 0.f;
  for (int m = lane; m < c; m += 64) s += nbrW[(size_t)r * CAP + m];
  for (int m = 32; m > 0; m >>= 1) s += __shfl_xor(s, m, 64);
  if (lane == 0) Dv[r] = (s > 0.f) ? rsqrtf(s) : 0.f;
}

// ---------- kernel 7: gPsi ----------
__global__ __launch_bounds__(256) void k_gpsi(const float* __restrict__ Psi,
                                              const int* __restrict__ cnt,
                                              const int* __restrict__ nbrJ,
                                              const float* __restrict__ nbrW,
                                              const float* __restrict__ Dv,
                                              float* __restrict__ gP) {
  const int i = blockIdx.x;
  const int tid = threadIdx.x;
  __shared__ int sJ[CAP];
  __shared__ float sW[CAP];
  const int c = min(cnt[i], CAP);
  if (tid < c) {
    const int j = nbrJ[(size_t)i * CAP + tid];
    sJ[tid] = j;
    sW[tid] = nbrW[(size_t)i * CAP + tid] * Dv[j];
  }
  __syncthreads();
  float acc = 0.f;
  for (int m = 0; m < c; ++m) acc += sW[m] * Psi[(size_t)sJ[m] * K_EIG + tid];
  gP[(size_t)i * K_EIG + tid] = acc * Dv[i];
}

// ---------- kernel 8: R = s^2 * Psi^T @ gPsi ----------
__global__ __launch_bounds__(256) void k_R(const float* __restrict__ Psi,
                                           const float* __restrict__ gP,
                                           float* __restrict__ Rm) {
  __shared__ float sP[128][32];
  __shared__ float sG[128][32];
  const int tid = threadIdx.x;
  const int at = (blockIdx.x >> 3) * 32;
  const int bt = (blockIdx.x & 7) * 32;
  const int a = tid & 31;
  const int bg = tid >> 5;
  float acc[4] = {0.f, 0.f, 0.f, 0.f};
  for (int nt = 0; nt < N_TOK / 128; ++nt) {
    __syncthreads();
    for (int idx = tid; idx < 128 * 32; idx += 256) {
      const int r = idx >> 5, cc = idx & 31;
      sP[r][cc] = Psi[(size_t)(nt * 128 + r) * K_EIG + at + cc];
      sG[r][cc] = gP[(size_t)(nt * 128 + r) * K_EIG + bt + cc];
    }
    __syncthreads();
#pragma unroll 4
    for (int r = 0; r < 128; ++r) {
      const float va = sP[r][a];
      const float4 g = *(const float4*)&sG[r][bg * 4];
      acc[0] += va * g.x; acc[1] += va * g.y; acc[2] += va * g.z; acc[3] += va * g.w;
    }
  }
  const float s2 = (10.f / 8192.f) * (10.f / 8192.f);
#pragma unroll
  for (int jj = 0; jj < 4; ++jj)
    Rm[(size_t)(at + a) * K_EIG + bt + bg * 4 + jj] = acc[jj] * s2;
}

// ---------- kernel 9: final scalars ----------
__global__ void k_final(const float* __restrict__ Rm, float* __restrict__ out) {
  __shared__ double st[256];
  __shared__ double sr[256];
  const int tid = threadIdx.x;
  double tl = 0.0, rg = 0.0;
  for (int i = tid; i < K_EIG * K_EIG; i += 256) {
    const int a = i >> 8, b = i & 255;
    const double v = (double)Rm[i];
    if (a == b) tl += v;
    else if (b > a) rg += v * v;
  }
  st[tid] = tl; sr[tid] = rg;
  __syncthreads();
  for (int s = 128; s > 0; s >>= 1) {
    if (tid < s) { st[tid] += st[tid + s]; sr[tid] += sr[tid + s]; }
    __syncthreads();
  }
  if (tid == 0) {
    out[0] = (float)(-st[0]);
    out[1] = (float)(sr[0] * 0.05);
  }
}

extern "C" void kernel_launch(void* const* d_in, const int* in_sizes, int n_in,
                              void* d_out, int out_size, void* d_ws, size_t ws_size,
                              hipStream_t stream) {
  const float* FF = (const float*)d_in[0];
  const float* Psi = (const float*)d_in[1];
  float* out = (float*)d_out;
  float* ws = (float*)d_ws;

  size_t o = 0;
  ushort_t* FFbf = (ushort_t*)(ws + o); o += (size_t)N_TOK * D_FEAT / 2;
  float* rn  = ws + o; o += N_TOK;
  float* sqv = ws + o; o += N_TOK;
  float* pd  = ws + o; o += (size_t)N_TOK * NCHUNK * 16;
  int*   pi  = (int*)(ws + o); o += (size_t)N_TOK * NCHUNK * 16;
  float* tv  = ws + o; o += (size_t)N_TOK * KNN;
  int*   tj  = (int*)(ws + o); o += (size_t)N_TOK * KNN;
  int*   cnt = (int*)(ws + o); o += N_TOK;
  float* Rm  = ws + o; o += (size_t)K_EIG * K_EIG;
  // region X: Cs (32 MB u16 keys) aliased with {nbrJ, nbrW, Dv, gP} — Cs dead after k_rescore
  char* X = (char*)(ws + o);
  ushort_t* Cs = (ushort_t*)X;
  int*   nbrJ = (int*)X;
  float* nbrW = (float*)(X + (size_t)N_TOK * CAP * 4);
  float* Dv   = (float*)(X + 2 * (size_t)N_TOK * CAP * 4);
  float* gP   = (float*)(X + 2 * (size_t)N_TOK * CAP * 4 + (size_t)N_TOK * 4);

  k_norm<<<N_TOK, 256, 0, stream>>>(FF, FFbf, rn, sqv);
  for (int c = 0; c < NCHUNK; ++c) {
    k_gemm<<<(N_TOK / 128) * (CHUNK / 128), 256, 0, stream>>>(FFbf, Cs, c * CHUNK);
    k_sel<<<N_TOK / 4, 256, 0, stream>>>(Cs, c, pd, pi);
  }
  k_rescore<<<N_TOK, 256, 0, stream>>>(FF, rn, sqv, pd, pi, tv, tj);
  hipMemsetAsync(cnt, 0, N_TOK * sizeof(int), stream);
  k_scatter<<<(N_TOK * KNN + 255) / 256, 256, 0, stream>>>(tv, tj, cnt, nbrJ, nbrW);
  k_degree<<<N_TOK / 4, 256, 0, stream>>>(cnt, nbrW, Dv);
  k_gpsi<<<N_TOK, 256, 0, stream>>>(Psi, cnt, nbrJ, nbrW, Dv, gP);
  k_R<<<64, 256, 0, stream>>>(Psi, gP, Rm);
  k_final<<<1, 256, 0, stream>>>(Rm, out);
}

// Round 4
// 649.062 us; speedup vs baseline: 5.3909x; 1.3448x over previous
//
#include <hip/hip_runtime.h>
#include <math.h>

#define N_TOK 8192
#define D_FEAT 768
#define K_EIG 256
#define KNN 10
#define CAP 256
#define NCHUNK 4
#define CHUNK 2048

typedef unsigned short ushort_t;
typedef float f32x4 __attribute__((ext_vector_type(4)));
typedef short bf16x8 __attribute__((ext_vector_type(8)));
typedef unsigned short u16x8 __attribute__((ext_vector_type(8)));
typedef unsigned short u16x4 __attribute__((ext_vector_type(4)));

__device__ inline float u2f(unsigned u) { union { unsigned u; float f; } c; c.u = u; return c.f; }
__device__ inline unsigned f2u(float f) { union { unsigned u; float f; } c; c.f = f; return c.u; }
__device__ inline ushort_t f2bf_rne(float f) {
  const unsigned u = f2u(f);
  return (ushort_t)((u + 0x7fffu + ((u >> 16) & 1u)) >> 16);
}
// monotone u16 key from f32 (truncate to bf16, flip for total order)
__device__ inline ushort_t f2key(float f) {
  const unsigned h = f2u(f) >> 16;
  return (ushort_t)((h & 0x8000u) ? (h ^ 0xFFFFu) : (h | 0x8000u));
}
__device__ inline float key2f(unsigned k) {
  const unsigned h = (k & 0x8000u) ? (k ^ 0x8000u) : (k ^ 0xFFFFu);
  return u2f(h << 16);
}
__device__ inline unsigned wave_max_u32(unsigned m) {
#pragma unroll
  for (int s = 1; s < 64; s <<= 1) m = max(m, (unsigned)__shfl_xor((int)m, s, 64));
  return m;
}

// ---------- kernel 1: row stats + bf16 normalized copy (vectorized) ----------
__global__ __launch_bounds__(192) void k_norm(const float* __restrict__ FF,
                                              ushort_t* __restrict__ FFbf,
                                              float* __restrict__ rn,
                                              float* __restrict__ sqv) {
  const int row = blockIdx.x;
  const int tid = threadIdx.x;
  const float4 v = *(const float4*)&FF[(size_t)row * D_FEAT + tid * 4];
  float s = v.x * v.x + v.y * v.y + v.z * v.z + v.w * v.w;
  __shared__ float red[3];
  for (int m = 32; m > 0; m >>= 1) s += __shfl_xor(s, m, 64);
  if ((tid & 63) == 0) red[tid >> 6] = s;
  __syncthreads();
  const float tot = red[0] + red[1] + red[2];
  const float scale = 1.f / fmaxf(sqrtf(tot), 1e-12f);
  float4 w;
  w.x = v.x * scale; w.y = v.y * scale; w.z = v.z * scale; w.w = v.w * scale;
  float s2 = w.x * w.x + w.y * w.y + w.z * w.z + w.w * w.w;
  u16x4 o;
  o[0] = f2bf_rne(w.x); o[1] = f2bf_rne(w.y); o[2] = f2bf_rne(w.z); o[3] = f2bf_rne(w.w);
  *(u16x4*)&FFbf[(size_t)row * D_FEAT + tid * 4] = o;
  for (int m = 32; m > 0; m >>= 1) s2 += __shfl_xor(s2, m, 64);
  __syncthreads();
  if ((tid & 63) == 0) red[tid >> 6] = s2;
  __syncthreads();
  if (tid == 0) { sqv[row] = red[0] + red[1] + red[2]; rn[row] = scale; }
}

// ---------- kernel 2: bf16 MFMA GEMM chunk -> u16 keys + group-of-8 maxes ----------
#define AS1(p) ((const __attribute__((address_space(1))) void*)(p))
#define AS3(p) ((__attribute__((address_space(3))) void*)(p))

__global__ __launch_bounds__(256) void k_gemm(const ushort_t* __restrict__ FFbf,
                                              ushort_t* __restrict__ Cs,
                                              ushort_t* __restrict__ Gmax,
                                              int cbase) {
  __shared__ ushort_t smem[16384];  // 32KB: staging (2buf A + 2buf B) then C-tile
  const int tid = threadIdx.x;
  const int mb = blockIdx.x & 63;
  const int nb = blockIdx.x >> 6;
  const int rbase = mb * 128;
  const int cb = cbase + nb * 128;
  const int w = tid >> 6, lane = tid & 63;
  const int wr = w >> 1, wc = w & 1;
  const int fr = lane & 15;
  const int kg = lane >> 4;
  const int srow = tid >> 2, skq = tid & 3;

  f32x4 acc[4][4];
#pragma unroll
  for (int m = 0; m < 4; ++m)
#pragma unroll
    for (int n = 0; n < 4; ++n) acc[m][n] = (f32x4){0.f, 0.f, 0.f, 0.f};

#define STAGE(b, kt) do { \
    const ushort_t* ga = FFbf + (size_t)(rbase + srow) * D_FEAT + (kt) * 32 + skq * 8; \
    const ushort_t* gb = FFbf + (size_t)(cb + srow) * D_FEAT + (kt) * 32 + skq * 8; \
    char* abase = (char*)&smem[(b) * 4096]; \
    char* bbase = (char*)&smem[8192 + (b) * 4096]; \
    __builtin_amdgcn_global_load_lds(AS1(ga), AS3(abase + tid * 16), 16, 0, 0); \
    __builtin_amdgcn_global_load_lds(AS1(gb), AS3(bbase + tid * 16), 16, 0, 0); \
    __builtin_amdgcn_global_load_lds(AS1(ga + (size_t)64 * D_FEAT), AS3(abase + 4096 + tid * 16), 16, 0, 0); \
    __builtin_amdgcn_global_load_lds(AS1(gb + (size_t)64 * D_FEAT), AS3(bbase + 4096 + tid * 16), 16, 0, 0); \
  } while (0)

  STAGE(0, 0);
  int buf = 0;
  for (int kt = 0; kt < D_FEAT / 32; ++kt) {
    __syncthreads();
    if (kt + 1 < D_FEAT / 32) STAGE(buf ^ 1, kt + 1);
    bf16x8 af[4], bfr[4];
#pragma unroll
    for (int m = 0; m < 4; ++m)
      af[m] = *(const bf16x8*)&smem[buf * 4096 + (wr * 64 + m * 16 + fr) * 32 + kg * 8];
#pragma unroll
    for (int n = 0; n < 4; ++n)
      bfr[n] = *(const bf16x8*)&smem[8192 + buf * 4096 + (wc * 64 + n * 16 + fr) * 32 + kg * 8];
#pragma unroll
    for (int m = 0; m < 4; ++m)
#pragma unroll
      for (int n = 0; n < 4; ++n)
        acc[m][n] = __builtin_amdgcn_mfma_f32_16x16x32_bf16(af[m], bfr[n], acc[m][n], 0, 0, 0);
    buf ^= 1;
  }
#undef STAGE

  // epilogue: keys -> LDS [128][128] u16
  __syncthreads();
#pragma unroll
  for (int m = 0; m < 4; ++m)
#pragma unroll
    for (int n = 0; n < 4; ++n)
#pragma unroll
      for (int r = 0; r < 4; ++r)
        smem[(wr * 64 + m * 16 + kg * 4 + r) * 128 + wc * 64 + n * 16 + fr] = f2key(acc[m][n][r]);
  __syncthreads();
  // coalesced 16B stores of the key tile
#pragma unroll
  for (int i = 0; i < 8; ++i) {
    const int off = i * 4096 + tid * 16;       // byte offset in 32KB tile
    const int row = off >> 8;                  // 256B per tile row
    const int colb = off & 255;
    const u16x8 v = *(const u16x8*)((const char*)smem + off);
    *(u16x8*)((char*)Cs + (size_t)(rbase + row) * (CHUNK * 2) + (size_t)nb * 256 + colb) = v;
  }
  // group-of-8 column maxes -> Gmax[8192][256]
  {
    const int r2 = tid >> 1;
    const int gh = (tid & 1) * 8;
    u16x8 gmv;
#pragma unroll
    for (int g = 0; g < 8; ++g) {
      const u16x8 grp = *(const u16x8*)&smem[r2 * 128 + (gh + g) * 8];
      unsigned mx = 0;
#pragma unroll
      for (int j = 0; j < 8; ++j) mx = max(mx, (unsigned)(ushort_t)grp[j]);
      gmv[g] = (ushort_t)mx;
    }
    *(u16x8*)&Gmax[(size_t)(rbase + r2) * 256 + nb * 16 + gh] = gmv;
  }
}

// ---------- kernel 3: exact per-row top-16 from Gmax + winning-group gather ----------
__global__ __launch_bounds__(256) void k_sel(const ushort_t* __restrict__ Cs,
                                             const ushort_t* __restrict__ Gmax,
                                             int chunk,
                                             float* __restrict__ pd, int* __restrict__ pi) {
  const int tid = threadIdx.x;
  const int lane = tid & 63;
  const int row = blockIdx.x * 4 + (tid >> 6);
  const ushort_t* src = Cs + (size_t)row * CHUNK;

  // phase 1: top-16 groups from precomputed group maxes
  const u16x4 gm = *(const u16x4*)&Gmax[(size_t)row * 256 + lane * 4];
  unsigned cur[4];
#pragma unroll
  for (int k = 0; k < 4; ++k)
    cur[k] = (((unsigned)(ushort_t)gm[k]) << 16) | (unsigned)(lane * 4 + k);
  unsigned keep = 0;
#pragma unroll
  for (int r = 0; r < 16; ++r) {
    unsigned m = max(max(cur[0], cur[1]), max(cur[2], cur[3]));
    m = wave_max_u32(m);
    if (lane == r) keep = m;
    const unsigned gid = m & 0xFFu;
    if (lane == (int)(gid >> 2)) {
      const int sl = (int)(gid & 3u);
#pragma unroll
      for (int k = 0; k < 4; ++k)
        if (k == sl) cur[k] = 0;
    }
  }
  // phase 2: gather 16 winning groups (128 elems), extract exact top-16
  const unsigned gid2 = keep & 0xFFu;  // valid for lanes 0..15
  unsigned E[8];
  if (lane < 16) {
    const u16x8 g = *(const u16x8*)&src[gid2 * 8];
#pragma unroll
    for (int j = 0; j < 8; ++j)
      E[j] = (((unsigned)(ushort_t)g[j]) << 16) | (gid2 * 8 + (unsigned)j);
  } else {
#pragma unroll
    for (int j = 0; j < 8; ++j) E[j] = 0;
  }
  unsigned keep2 = 0;
#pragma unroll
  for (int r = 0; r < 16; ++r) {
    unsigned m = E[0];
#pragma unroll
    for (int j = 1; j < 8; ++j) m = max(m, E[j]);
    m = wave_max_u32(m);
    if (lane == r) keep2 = m;
    const unsigned col = m & 0xFFFFu;
    const bool mine = (lane < 16) && ((col >> 3) == gid2);
    const int sl = (int)(col & 7u);
#pragma unroll
    for (int j = 0; j < 8; ++j)
      if (mine && j == sl) E[j] = 0;
  }
  if (lane < 16) {
    pd[((size_t)row * NCHUNK + chunk) * 16 + lane] = key2f(keep2 >> 16);
    pi[((size_t)row * NCHUNK + chunk) * 16 + lane] = chunk * CHUNK + (int)(keep2 & 0xFFFFu);
  }
}

// ---------- kernel 4: exact fp32 rescore, one wave per row ----------
__global__ __launch_bounds__(256) void k_rescore(const float* __restrict__ FF,
                                                 const float* __restrict__ rn,
                                                 const float* __restrict__ sqv,
                                                 const float* __restrict__ pd,
                                                 const int* __restrict__ pi,
                                                 float* __restrict__ tv, int* __restrict__ tj) {
  const int tid = threadIdx.x;
  const int lane = tid & 63;
  const int row = blockIdx.x * 4 + (tid >> 6);

  // phase A: top-16 of the 64 chunk candidates by bf16 key (branchless extract)
  const float pdv = pd[(size_t)row * 64 + lane];
  const int myj = pi[(size_t)row * 64 + lane];
  unsigned cur = (((unsigned)f2key(pdv)) << 16) | (unsigned)lane;
  int selj = 0;  // lanes 0..15: j of the r-th selected candidate
#pragma unroll
  for (int r = 0; r < 16; ++r) {
    const unsigned m = wave_max_u32(cur);
    const int wln = (int)(m & 63u);
    const int jw = __shfl(myj, wln, 64);
    if (lane == r) selj = jw;
    if (lane == wln) cur = 0;
  }

  // phase B: exact fp32 dots, full-wave per candidate
  const float si = rn[row];
  const float sqi = sqv[row];
  const float* fi = FF + (size_t)row * D_FEAT;
  float4 a0 = *(const float4*)&fi[lane * 4];
  float4 a1 = *(const float4*)&fi[256 + lane * 4];
  float4 a2 = *(const float4*)&fi[512 + lane * 4];
  // round a*scale once -> exactly the reference's FFn elements
  a0.x *= si; a0.y *= si; a0.z *= si; a0.w *= si;
  a1.x *= si; a1.y *= si; a1.z *= si; a1.w *= si;
  a2.x *= si; a2.y *= si; a2.z *= si; a2.w *= si;

  float dsc_l = 0.f, dvl_l = 0.f; int j_l = 0;
#pragma unroll 4
  for (int c = 0; c < 16; ++c) {
    const int j = __shfl(selj, c, 64);
    const float sj = rn[j];
    const float* fj = FF + (size_t)j * D_FEAT;
    const float4 b0 = *(const float4*)&fj[lane * 4];
    const float4 b1 = *(const float4*)&fj[256 + lane * 4];
    const float4 b2 = *(const float4*)&fj[512 + lane * 4];
    float acc = 0.f;
    acc = fmaf(a0.x, b0.x * sj, acc); acc = fmaf(a0.y, b0.y * sj, acc);
    acc = fmaf(a0.z, b0.z * sj, acc); acc = fmaf(a0.w, b0.w * sj, acc);
    acc = fmaf(a1.x, b1.x * sj, acc); acc = fmaf(a1.y, b1.y * sj, acc);
    acc = fmaf(a1.z, b1.z * sj, acc); acc = fmaf(a1.w, b1.w * sj, acc);
    acc = fmaf(a2.x, b2.x * sj, acc); acc = fmaf(a2.y, b2.y * sj, acc);
    acc = fmaf(a2.z, b2.z * sj, acc); acc = fmaf(a2.w, b2.w * sj, acc);
#pragma unroll
    for (int m = 32; m > 0; m >>= 1) acc += __shfl_xor(acc, m, 64);
    if (lane == c) {
      const float sqj = sqv[j];
      j_l = j;
      dsc_l = acc - 0.5f * sqj;  // exactly monotone with the exp comparator
      dvl_l = expf(-0.5f * (sqi + sqj - 2.f * acc));
    }
  }

  // phase C: top-10 of 16 by exact dsc (branchless extract), write tv/tj
  unsigned fk = 0;
  if (lane < 16) {
    const unsigned u = f2u(dsc_l);
    fk = u ^ ((u >> 31) ? 0xFFFFFFFFu : 0x80000000u);
  }
#pragma unroll
  for (int s = 0; s < 10; ++s) {
    const unsigned m = wave_max_u32(fk);
    const unsigned long long bal = __ballot(fk == m);
    const int wln = __ffsll((unsigned long long)bal) - 1;
    const float tvv = __shfl(dvl_l, wln, 64);
    const int tjj = __shfl(j_l, wln, 64);
    if (lane == s) {
      tv[(size_t)row * KNN + s] = tvv;
      tj[(size_t)row * KNN + s] = tjj;
    }
    if (lane == wln) fk = 0;
  }
}

// ---------- kernel 5: scatter both edge directions ----------
__global__ void k_scatter(const float* __restrict__ tv, const int* __restrict__ tj,
                          int* __restrict__ cnt, int* __restrict__ nbrJ,
                          float* __restrict__ nbrW) {
  const int e = blockIdx.x * blockDim.x + threadIdx.x;
  if (e >= N_TOK * KNN) return;
  const int i = e / KNN;
  const int j = tj[e];
  if (j == i) return;
  const float w = 0.5f * tv[e];
  const int p = atomicAdd(&cnt[i], 1);
  if (p < CAP) { nbrJ[(size_t)i * CAP + p] = j; nbrW[(size_t)i * CAP + p] = w; }
  const int q = atomicAdd(&cnt[j], 1);
  if (q < CAP) { nbrJ[(size_t)j * CAP + q] = i; nbrW[(size_t)j * CAP + q] = w; }
}

// ---------- kernel 6: degree + rsqrt ----------
__global__ void k_degree(const int* __restrict__ cnt, const float* __restrict__ nbrW,
                         float* __restrict__ Dv) {
  const int r = blockIdx.x * 4 + (threadIdx.x >> 6);
  const int lane = threadIdx.x & 63;
  const int c = min(cnt[r], CAP);
  float s = 0.f;
  for (int m = lane; m < c; m += 64) s += nbrW[(size_t)r * CAP + m];
  for (int m = 32; m > 0; m >>= 1) s += __shfl_xor(s, m, 64);
  if (lane == 0) Dv[r] = (s > 0.f) ? rsqrtf(s) : 0.f;
}

// ---------- kernel 7: gPsi ----------
__global__ __launch_bounds__(256) void k_gpsi(const float* __restrict__ Psi,
                                              const int* __restrict__ cnt,
                                              const int* __restrict__ nbrJ,
                                              const float* __restrict__ nbrW,
                                              const float* __restrict__ Dv,
                                              float* __restrict__ gP) {
  const int i = blockIdx.x;
  const int tid = threadIdx.x;
  __shared__ int sJ[CAP];
  __shared__ float sW[CAP];
  const int c = min(cnt[i], CAP);
  if (tid < c) {
    const int j = nbrJ[(size_t)i * CAP + tid];
    sJ[tid] = j;
    sW[tid] = nbrW[(size_t)i * CAP + tid] * Dv[j];
  }
  __syncthreads();
  float acc = 0.f;
  for (int m = 0; m < c; ++m) acc += sW[m] * Psi[(size_t)sJ[m] * K_EIG + tid];
  gP[(size_t)i * K_EIG + tid] = acc * Dv[i];
}

// ---------- kernel 8: R = s^2 * Psi^T @ gPsi ----------
__global__ __launch_bounds__(256) void k_R(const float* __restrict__ Psi,
                                           const float* __restrict__ gP,
                                           float* __restrict__ Rm) {
  __shared__ float sP[128][32];
  __shared__ float sG[128][32];
  const int tid = threadIdx.x;
  const int at = (blockIdx.x >> 3) * 32;
  const int bt = (blockIdx.x & 7) * 32;
  const int a = tid & 31;
  const int bg = tid >> 5;
  float acc[4] = {0.f, 0.f, 0.f, 0.f};
  for (int nt = 0; nt < N_TOK / 128; ++nt) {
    __syncthreads();
    for (int idx = tid; idx < 128 * 32; idx += 256) {
      const int r = idx >> 5, cc = idx & 31;
      sP[r][cc] = Psi[(size_t)(nt * 128 + r) * K_EIG + at + cc];
      sG[r][cc] = gP[(size_t)(nt * 128 + r) * K_EIG + bt + cc];
    }
    __syncthreads();
#pragma unroll 4
    for (int r = 0; r < 128; ++r) {
      const float va = sP[r][a];
      const float4 g = *(const float4*)&sG[r][bg * 4];
      acc[0] += va * g.x; acc[1] += va * g.y; acc[2] += va * g.z; acc[3] += va * g.w;
    }
  }
  const float s2 = (10.f / 8192.f) * (10.f / 8192.f);
#pragma unroll
  for (int jj = 0; jj < 4; ++jj)
    Rm[(size_t)(at + a) * K_EIG + bt + bg * 4 + jj] = acc[jj] * s2;
}

// ---------- kernel 9: final scalars ----------
__global__ void k_final(const float* __restrict__ Rm, float* __restrict__ out) {
  __shared__ double st[256];
  __shared__ double sr[256];
  const int tid = threadIdx.x;
  double tl = 0.0, rg = 0.0;
  for (int i = tid; i < K_EIG * K_EIG; i += 256) {
    const int a = i >> 8, b = i & 255;
    const double v = (double)Rm[i];
    if (a == b) tl += v;
    else if (b > a) rg += v * v;
  }
  st[tid] = tl; sr[tid] = rg;
  __syncthreads();
  for (int s = 128; s > 0; s >>= 1) {
    if (tid < s) { st[tid] += st[tid + s]; sr[tid] += sr[tid + s]; }
    __syncthreads();
  }
  if (tid == 0) {
    out[0] = (float)(-st[0]);
    out[1] = (float)(sr[0] * 0.05);
  }
}

extern "C" void kernel_launch(void* const* d_in, const int* in_sizes, int n_in,
                              void* d_out, int out_size, void* d_ws, size_t ws_size,
                              hipStream_t stream) {
  const float* FF = (const float*)d_in[0];
  const float* Psi = (const float*)d_in[1];
  float* out = (float*)d_out;
  float* ws = (float*)d_ws;

  size_t o = 0;
  ushort_t* FFbf = (ushort_t*)(ws + o); o += (size_t)N_TOK * D_FEAT / 2;
  float* rn  = ws + o; o += N_TOK;
  float* sqv = ws + o; o += N_TOK;
  float* pd  = ws + o; o += (size_t)N_TOK * NCHUNK * 16;
  int*   pi  = (int*)(ws + o); o += (size_t)N_TOK * NCHUNK * 16;
  float* tv  = ws + o; o += (size_t)N_TOK * KNN;
  int*   tj  = (int*)(ws + o); o += (size_t)N_TOK * KNN;
  int*   cnt = (int*)(ws + o); o += N_TOK;
  float* Rm  = ws + o; o += (size_t)K_EIG * K_EIG;
  ushort_t* Gmax = (ushort_t*)(ws + o); o += (size_t)N_TOK * 256 / 2;  // 4 MB
  // region X: Cs (32 MB u16 keys) aliased with {nbrJ, nbrW, Dv, gP} — Cs dead after k_rescore
  char* X = (char*)(ws + o);
  ushort_t* Cs = (ushort_t*)X;
  int*   nbrJ = (int*)X;
  float* nbrW = (float*)(X + (size_t)N_TOK * CAP * 4);
  float* Dv   = (float*)(X + 2 * (size_t)N_TOK * CAP * 4);
  float* gP   = (float*)(X + 2 * (size_t)N_TOK * CAP * 4 + (size_t)N_TOK * 4);

  k_norm<<<N_TOK, 192, 0, stream>>>(FF, FFbf, rn, sqv);
  for (int c = 0; c < NCHUNK; ++c) {
    k_gemm<<<(N_TOK / 128) * (CHUNK / 128), 256, 0, stream>>>(FFbf, Cs, Gmax, c * CHUNK);
    k_sel<<<N_TOK / 4, 256, 0, stream>>>(Cs, Gmax, c, pd, pi);
  }
  k_rescore<<<N_TOK / 4, 256, 0, stream>>>(FF, rn, sqv, pd, pi, tv, tj);
  hipMemsetAsync(cnt, 0, N_TOK * sizeof(int), stream);
  k_scatter<<<(N_TOK * KNN + 255) / 256, 256, 0, stream>>>(tv, tj, cnt, nbrJ, nbrW);
  k_degree<<<N_TOK / 4, 256, 0, stream>>>(cnt, nbrW, Dv);
  k_gpsi<<<N_TOK, 256, 0, stream>>>(Psi, cnt, nbrJ, nbrW, Dv, gP);
  k_R<<<64, 256, 0, stream>>>(Psi, gP, Rm);
  k_final<<<1, 256, 0, stream>>>(Rm, out);
}

// Round 5
// 392.486 us; speedup vs baseline: 8.9150x; 1.6537x over previous
//
#include <hip/hip_runtime.h>
#include <math.h>

#define N_TOK 8192
#define D_FEAT 768
#define K_EIG 256
#define KNN 10
#define CAP 256
#define NCHUNK 4
#define CHUNK 2048

typedef unsigned short ushort_t;
typedef float f32x4 __attribute__((ext_vector_type(4)));
typedef short bf16x8 __attribute__((ext_vector_type(8)));
typedef unsigned short u16x8 __attribute__((ext_vector_type(8)));
typedef unsigned short u16x4 __attribute__((ext_vector_type(4)));

__device__ inline float u2f(unsigned u) { union { unsigned u; float f; } c; c.u = u; return c.f; }
__device__ inline unsigned f2u(float f) { union { unsigned u; float f; } c; c.f = f; return c.u; }
__device__ inline ushort_t f2bf_rne(float f) {
  const unsigned u = f2u(f);
  return (ushort_t)((u + 0x7fffu + ((u >> 16) & 1u)) >> 16);
}
// monotone u16 key from f32 (truncate to bf16, flip for total order)
__device__ inline ushort_t f2key(float f) {
  const unsigned h = f2u(f) >> 16;
  return (ushort_t)((h & 0x8000u) ? (h ^ 0xFFFFu) : (h | 0x8000u));
}
__device__ inline float key2f(unsigned k) {
  const unsigned h = (k & 0x8000u) ? (k ^ 0x8000u) : (k ^ 0xFFFFu);
  return u2f(h << 16);
}
__device__ inline unsigned wave_max_u32(unsigned m) {
#pragma unroll
  for (int s = 1; s < 64; s <<= 1) m = max(m, (unsigned)__shfl_xor((int)m, s, 64));
  return m;
}

// ---------- kernel 1: row stats + bf16 normalized copy (vectorized) ----------
__global__ __launch_bounds__(192) void k_norm(const float* __restrict__ FF,
                                              ushort_t* __restrict__ FFbf,
                                              float* __restrict__ rn,
                                              float* __restrict__ sqv) {
  const int row = blockIdx.x;
  const int tid = threadIdx.x;
  const float4 v = *(const float4*)&FF[(size_t)row * D_FEAT + tid * 4];
  float s = v.x * v.x + v.y * v.y + v.z * v.z + v.w * v.w;
  __shared__ float red[3];
  for (int m = 32; m > 0; m >>= 1) s += __shfl_xor(s, m, 64);
  if ((tid & 63) == 0) red[tid >> 6] = s;
  __syncthreads();
  const float tot = red[0] + red[1] + red[2];
  const float scale = 1.f / fmaxf(sqrtf(tot), 1e-12f);
  float4 w;
  w.x = v.x * scale; w.y = v.y * scale; w.z = v.z * scale; w.w = v.w * scale;
  float s2 = w.x * w.x + w.y * w.y + w.z * w.z + w.w * w.w;
  u16x4 o;
  o[0] = f2bf_rne(w.x); o[1] = f2bf_rne(w.y); o[2] = f2bf_rne(w.z); o[3] = f2bf_rne(w.w);
  *(u16x4*)&FFbf[(size_t)row * D_FEAT + tid * 4] = o;
  for (int m = 32; m > 0; m >>= 1) s2 += __shfl_xor(s2, m, 64);
  __syncthreads();
  if ((tid & 63) == 0) red[tid >> 6] = s2;
  __syncthreads();
  if (tid == 0) { sqv[row] = red[0] + red[1] + red[2]; rn[row] = scale; }
}

// ---------- kernel 2: bf16 MFMA GEMM chunk -> u16 keys + group-of-8 maxes ----------
#define AS1(p) ((const __attribute__((address_space(1))) void*)(p))
#define AS3(p) ((__attribute__((address_space(3))) void*)(p))

__global__ __launch_bounds__(256) void k_gemm(const ushort_t* __restrict__ FFbf,
                                              ushort_t* __restrict__ Cs,
                                              ushort_t* __restrict__ Gmax,
                                              int cbase) {
  __shared__ ushort_t smem[16384];  // 32KB: staging (2buf A + 2buf B) then C-tile
  const int tid = threadIdx.x;
  const int mb = blockIdx.x & 63;
  const int nb = blockIdx.x >> 6;
  const int rbase = mb * 128;
  const int cb = cbase + nb * 128;
  const int w = tid >> 6, lane = tid & 63;
  const int wr = w >> 1, wc = w & 1;
  const int fr = lane & 15;
  const int kg = lane >> 4;
  const int srow = tid >> 2, skq = tid & 3;

  f32x4 acc[4][4];
#pragma unroll
  for (int m = 0; m < 4; ++m)
#pragma unroll
    for (int n = 0; n < 4; ++n) acc[m][n] = (f32x4){0.f, 0.f, 0.f, 0.f};

#define STAGE(b, kt) do { \
    const ushort_t* ga = FFbf + (size_t)(rbase + srow) * D_FEAT + (kt) * 32 + skq * 8; \
    const ushort_t* gb = FFbf + (size_t)(cb + srow) * D_FEAT + (kt) * 32 + skq * 8; \
    char* abase = (char*)&smem[(b) * 4096]; \
    char* bbase = (char*)&smem[8192 + (b) * 4096]; \
    __builtin_amdgcn_global_load_lds(AS1(ga), AS3(abase + tid * 16), 16, 0, 0); \
    __builtin_amdgcn_global_load_lds(AS1(gb), AS3(bbase + tid * 16), 16, 0, 0); \
    __builtin_amdgcn_global_load_lds(AS1(ga + (size_t)64 * D_FEAT), AS3(abase + 4096 + tid * 16), 16, 0, 0); \
    __builtin_amdgcn_global_load_lds(AS1(gb + (size_t)64 * D_FEAT), AS3(bbase + 4096 + tid * 16), 16, 0, 0); \
  } while (0)

  STAGE(0, 0);
  int buf = 0;
  for (int kt = 0; kt < D_FEAT / 32; ++kt) {
    __syncthreads();
    if (kt + 1 < D_FEAT / 32) STAGE(buf ^ 1, kt + 1);
    bf16x8 af[4], bfr[4];
#pragma unroll
    for (int m = 0; m < 4; ++m)
      af[m] = *(const bf16x8*)&smem[buf * 4096 + (wr * 64 + m * 16 + fr) * 32 + kg * 8];
#pragma unroll
    for (int n = 0; n < 4; ++n)
      bfr[n] = *(const bf16x8*)&smem[8192 + buf * 4096 + (wc * 64 + n * 16 + fr) * 32 + kg * 8];
#pragma unroll
    for (int m = 0; m < 4; ++m)
#pragma unroll
      for (int n = 0; n < 4; ++n)
        acc[m][n] = __builtin_amdgcn_mfma_f32_16x16x32_bf16(af[m], bfr[n], acc[m][n], 0, 0, 0);
    buf ^= 1;
  }
#undef STAGE

  // epilogue: keys -> LDS [128][128] u16
  __syncthreads();
#pragma unroll
  for (int m = 0; m < 4; ++m)
#pragma unroll
    for (int n = 0; n < 4; ++n)
#pragma unroll
      for (int r = 0; r < 4; ++r)
        smem[(wr * 64 + m * 16 + kg * 4 + r) * 128 + wc * 64 + n * 16 + fr] = f2key(acc[m][n][r]);
  __syncthreads();
  // coalesced 16B stores of the key tile
#pragma unroll
  for (int i = 0; i < 8; ++i) {
    const int off = i * 4096 + tid * 16;       // byte offset in 32KB tile
    const int row = off >> 8;                  // 256B per tile row
    const int colb = off & 255;
    const u16x8 v = *(const u16x8*)((const char*)smem + off);
    *(u16x8*)((char*)Cs + (size_t)(rbase + row) * (CHUNK * 2) + (size_t)nb * 256 + colb) = v;
  }
  // group-of-8 column maxes -> Gmax[8192][256]
  {
    const int r2 = tid >> 1;
    const int gh = (tid & 1) * 8;
    u16x8 gmv;
#pragma unroll
    for (int g = 0; g < 8; ++g) {
      const u16x8 grp = *(const u16x8*)&smem[r2 * 128 + (gh + g) * 8];
      unsigned mx = 0;
#pragma unroll
      for (int j = 0; j < 8; ++j) mx = max(mx, (unsigned)(ushort_t)grp[j]);
      gmv[g] = (ushort_t)mx;
    }
    *(u16x8*)&Gmax[(size_t)(rbase + r2) * 256 + nb * 16 + gh] = gmv;
  }
}

// ---------- kernel 3: exact per-row top-16 from Gmax + winning-group gather ----------
__global__ __launch_bounds__(256) void k_sel(const ushort_t* __restrict__ Cs,
                                             const ushort_t* __restrict__ Gmax,
                                             int chunk,
                                             float* __restrict__ pd, int* __restrict__ pi) {
  const int tid = threadIdx.x;
  const int lane = tid & 63;
  const int row = blockIdx.x * 4 + (tid >> 6);
  const ushort_t* src = Cs + (size_t)row * CHUNK;

  // phase 1: top-16 groups from precomputed group maxes
  const u16x4 gm = *(const u16x4*)&Gmax[(size_t)row * 256 + lane * 4];
  unsigned cur[4];
#pragma unroll
  for (int k = 0; k < 4; ++k)
    cur[k] = (((unsigned)(ushort_t)gm[k]) << 16) | (unsigned)(lane * 4 + k);
  unsigned keep = 0;
#pragma unroll
  for (int r = 0; r < 16; ++r) {
    unsigned m = max(max(cur[0], cur[1]), max(cur[2], cur[3]));
    m = wave_max_u32(m);
    if (lane == r) keep = m;
    const unsigned gid = m & 0xFFu;
    if (lane == (int)(gid >> 2)) {
      const int sl = (int)(gid & 3u);
#pragma unroll
      for (int k = 0; k < 4; ++k)
        if (k == sl) cur[k] = 0;
    }
  }
  // phase 2: gather 16 winning groups (128 elems), extract exact top-16
  const unsigned gid2 = keep & 0xFFu;  // valid for lanes 0..15
  unsigned E[8];
  if (lane < 16) {
    const u16x8 g = *(const u16x8*)&src[gid2 * 8];
#pragma unroll
    for (int j = 0; j < 8; ++j)
      E[j] = (((unsigned)(ushort_t)g[j]) << 16) | (gid2 * 8 + (unsigned)j);
  } else {
#pragma unroll
    for (int j = 0; j < 8; ++j) E[j] = 0;
  }
  unsigned keep2 = 0;
#pragma unroll
  for (int r = 0; r < 16; ++r) {
    unsigned m = E[0];
#pragma unroll
    for (int j = 1; j < 8; ++j) m = max(m, E[j]);
    m = wave_max_u32(m);
    if (lane == r) keep2 = m;
    const unsigned col = m & 0xFFFFu;
    const bool mine = (lane < 16) && ((col >> 3) == gid2);
    const int sl = (int)(col & 7u);
#pragma unroll
    for (int j = 0; j < 8; ++j)
      if (mine && j == sl) E[j] = 0;
  }
  if (lane < 16) {
    pd[((size_t)row * NCHUNK + chunk) * 16 + lane] = key2f(keep2 >> 16);
    pi[((size_t)row * NCHUNK + chunk) * 16 + lane] = chunk * CHUNK + (int)(keep2 & 0xFFFFu);
  }
}

// ---------- kernel 4: exact fp32 rescore, one wave per row ----------
__global__ __launch_bounds__(256) void k_rescore(const float* __restrict__ FF,
                                                 const float* __restrict__ rn,
                                                 const float* __restrict__ sqv,
                                                 const float* __restrict__ pd,
                                                 const int* __restrict__ pi,
                                                 float* __restrict__ tv, int* __restrict__ tj) {
  const int tid = threadIdx.x;
  const int lane = tid & 63;
  const int row = blockIdx.x * 4 + (tid >> 6);

  // phase A: top-16 of the 64 chunk candidates by bf16 key (branchless extract)
  const float pdv = pd[(size_t)row * 64 + lane];
  const int myj = pi[(size_t)row * 64 + lane];
  unsigned cur = (((unsigned)f2key(pdv)) << 16) | (unsigned)lane;
  int selj = 0;  // lanes 0..15: j of the r-th selected candidate
#pragma unroll
  for (int r = 0; r < 16; ++r) {
    const unsigned m = wave_max_u32(cur);
    const int wln = (int)(m & 63u);
    const int jw = __shfl(myj, wln, 64);
    if (lane == r) selj = jw;
    if (lane == wln) cur = 0;
  }

  // phase B: exact fp32 dots, full-wave per candidate
  const float si = rn[row];
  const float sqi = sqv[row];
  const float* fi = FF + (size_t)row * D_FEAT;
  float4 a0 = *(const float4*)&fi[lane * 4];
  float4 a1 = *(const float4*)&fi[256 + lane * 4];
  float4 a2 = *(const float4*)&fi[512 + lane * 4];
  // round a*scale once -> exactly the reference's FFn elements
  a0.x *= si; a0.y *= si; a0.z *= si; a0.w *= si;
  a1.x *= si; a1.y *= si; a1.z *= si; a1.w *= si;
  a2.x *= si; a2.y *= si; a2.z *= si; a2.w *= si;

  float dsc_l = 0.f, dvl_l = 0.f; int j_l = 0;
#pragma unroll 4
  for (int c = 0; c < 16; ++c) {
    const int j = __shfl(selj, c, 64);
    const float sj = rn[j];
    const float* fj = FF + (size_t)j * D_FEAT;
    const float4 b0 = *(const float4*)&fj[lane * 4];
    const float4 b1 = *(const float4*)&fj[256 + lane * 4];
    const float4 b2 = *(const float4*)&fj[512 + lane * 4];
    float acc = 0.f;
    acc = fmaf(a0.x, b0.x * sj, acc); acc = fmaf(a0.y, b0.y * sj, acc);
    acc = fmaf(a0.z, b0.z * sj, acc); acc = fmaf(a0.w, b0.w * sj, acc);
    acc = fmaf(a1.x, b1.x * sj, acc); acc = fmaf(a1.y, b1.y * sj, acc);
    acc = fmaf(a1.z, b1.z * sj, acc); acc = fmaf(a1.w, b1.w * sj, acc);
    acc = fmaf(a2.x, b2.x * sj, acc); acc = fmaf(a2.y, b2.y * sj, acc);
    acc = fmaf(a2.z, b2.z * sj, acc); acc = fmaf(a2.w, b2.w * sj, acc);
#pragma unroll
    for (int m = 32; m > 0; m >>= 1) acc += __shfl_xor(acc, m, 64);
    if (lane == c) {
      const float sqj = sqv[j];
      j_l = j;
      dsc_l = acc - 0.5f * sqj;  // exactly monotone with the exp comparator
      dvl_l = expf(-0.5f * (sqi + sqj - 2.f * acc));
    }
  }

  // phase C: top-10 of 16 by exact dsc (branchless extract), write tv/tj
  unsigned fk = 0;
  if (lane < 16) {
    const unsigned u = f2u(dsc_l);
    fk = u ^ ((u >> 31) ? 0xFFFFFFFFu : 0x80000000u);
  }
#pragma unroll
  for (int s = 0; s < 10; ++s) {
    const unsigned m = wave_max_u32(fk);
    const unsigned long long bal = __ballot(fk == m);
    const int wln = __ffsll((unsigned long long)bal) - 1;
    const float tvv = __shfl(dvl_l, wln, 64);
    const int tjj = __shfl(j_l, wln, 64);
    if (lane == s) {
      tv[(size_t)row * KNN + s] = tvv;
      tj[(size_t)row * KNN + s] = tjj;
    }
    if (lane == wln) fk = 0;
  }
}

// ---------- kernel 5: scatter both edge directions ----------
__global__ void k_scatter(const float* __restrict__ tv, const int* __restrict__ tj,
                          int* __restrict__ cnt, int* __restrict__ nbrJ,
                          float* __restrict__ nbrW) {
  const int e = blockIdx.x * blockDim.x + threadIdx.x;
  if (e >= N_TOK * KNN) return;
  const int i = e / KNN;
  const int j = tj[e];
  if (j == i) return;
  const float w = 0.5f * tv[e];
  const int p = atomicAdd(&cnt[i], 1);
  if (p < CAP) { nbrJ[(size_t)i * CAP + p] = j; nbrW[(size_t)i * CAP + p] = w; }
  const int q = atomicAdd(&cnt[j], 1);
  if (q < CAP) { nbrJ[(size_t)j * CAP + q] = i; nbrW[(size_t)j * CAP + q] = w; }
}

// ---------- kernel 6: degree + rsqrt ----------
__global__ void k_degree(const int* __restrict__ cnt, const float* __restrict__ nbrW,
                         float* __restrict__ Dv) {
  const int r = blockIdx.x * 4 + (threadIdx.x >> 6);
  const int lane = threadIdx.x & 63;
  const int c = min(cnt[r], CAP);
  float s = 0.f;
  for (int m = lane; m < c; m += 64) s += nbrW[(size_t)r * CAP + m];
  for (int m = 32; m > 0; m >>= 1) s += __shfl_xor(s, m, 64);
  if (lane == 0) Dv[r] = (s > 0.f) ? rsqrtf(s) : 0.f;
}

// ---------- kernel 7: gPsi ----------
__global__ __launch_bounds__(256) void k_gpsi(const float* __restrict__ Psi,
                                              const int* __restrict__ cnt,
                                              const int* __restrict__ nbrJ,
                                              const float* __restrict__ nbrW,
                                              const float* __restrict__ Dv,
                                              float* __restrict__ gP) {
  const int i = blockIdx.x;
  const int tid = threadIdx.x;
  __shared__ int sJ[CAP];
  __shared__ float sW[CAP];
  const int c = min(cnt[i], CAP);
  if (tid < c) {
    const int j = nbrJ[(size_t)i * CAP + tid];
    sJ[tid] = j;
    sW[tid] = nbrW[(size_t)i * CAP + tid] * Dv[j];
  }
  __syncthreads();
  float acc = 0.f;
  for (int m = 0; m < c; ++m) acc += sW[m] * Psi[(size_t)sJ[m] * K_EIG + tid];
  gP[(size_t)i * K_EIG + tid] = acc * Dv[i];
}

// ---------- kernel 8a: split-K partials of R = Psi^T @ gPsi ----------
// grid: 256 blocks = 16 K-slices (512 rows each) x 16 tiles (64x64 of 256x256)
__global__ __launch_bounds__(256) void k_Rpart(const float* __restrict__ Psi,
                                               const float* __restrict__ gP,
                                               float* __restrict__ Rp) {
  __shared__ float sP[64][68];
  __shared__ float sG[64][68];
  const int tid = threadIdx.x;
  const int ks = blockIdx.x >> 4;
  const int tile = blockIdx.x & 15;
  const int at = (tile >> 2) * 64;
  const int bt = (tile & 3) * 64;
  const int a4 = (tid & 15) * 4;
  const int b4 = (tid >> 4) * 4;
  const int lr = tid >> 2;

  float acc[4][4];
#pragma unroll
  for (int i = 0; i < 4; ++i)
#pragma unroll
    for (int j = 0; j < 4; ++j) acc[i][j] = 0.f;

  for (int rt = 0; rt < 8; ++rt) {
    const int r0 = ks * 512 + rt * 64;
    __syncthreads();
#pragma unroll
    for (int q = 0; q < 4; ++q) {
      const int seg = (tid & 3) + q * 4;
      *(float4*)&sP[lr][seg * 4] = *(const float4*)&Psi[(size_t)(r0 + lr) * K_EIG + at + seg * 4];
      *(float4*)&sG[lr][seg * 4] = *(const float4*)&gP[(size_t)(r0 + lr) * K_EIG + bt + seg * 4];
    }
    __syncthreads();
#pragma unroll 4
    for (int r = 0; r < 64; ++r) {
      const float4 pa = *(const float4*)&sP[r][a4];
      const float4 pg = *(const float4*)&sG[r][b4];
      acc[0][0] = fmaf(pa.x, pg.x, acc[0][0]); acc[0][1] = fmaf(pa.x, pg.y, acc[0][1]);
      acc[0][2] = fmaf(pa.x, pg.z, acc[0][2]); acc[0][3] = fmaf(pa.x, pg.w, acc[0][3]);
      acc[1][0] = fmaf(pa.y, pg.x, acc[1][0]); acc[1][1] = fmaf(pa.y, pg.y, acc[1][1]);
      acc[1][2] = fmaf(pa.y, pg.z, acc[1][2]); acc[1][3] = fmaf(pa.y, pg.w, acc[1][3]);
      acc[2][0] = fmaf(pa.z, pg.x, acc[2][0]); acc[2][1] = fmaf(pa.z, pg.y, acc[2][1]);
      acc[2][2] = fmaf(pa.z, pg.z, acc[2][2]); acc[2][3] = fmaf(pa.z, pg.w, acc[2][3]);
      acc[3][0] = fmaf(pa.w, pg.x, acc[3][0]); acc[3][1] = fmaf(pa.w, pg.y, acc[3][1]);
      acc[3][2] = fmaf(pa.w, pg.z, acc[3][2]); acc[3][3] = fmaf(pa.w, pg.w, acc[3][3]);
    }
  }
#pragma unroll
  for (int i = 0; i < 4; ++i) {
    float4 o; o.x = acc[i][0]; o.y = acc[i][1]; o.z = acc[i][2]; o.w = acc[i][3];
    *(float4*)&Rp[(size_t)ks * (K_EIG * K_EIG) + (size_t)(at + a4 + i) * K_EIG + bt + b4] = o;
  }
}

// ---------- kernel 8b: reduce 16 slices + partial trace/triu sums ----------
__global__ __launch_bounds__(256) void k_Rred(const float* __restrict__ Rp,
                                              double* __restrict__ part) {
  const int tid = threadIdx.x;
  const int e0 = blockIdx.x * 1024 + tid * 4;
  float4 s = {0.f, 0.f, 0.f, 0.f};
  for (int ks = 0; ks < 16; ++ks) {
    const float4 v = *(const float4*)&Rp[(size_t)ks * (K_EIG * K_EIG) + e0];
    s.x += v.x; s.y += v.y; s.z += v.z; s.w += v.w;
  }
  const float sc = (10.f / 8192.f) * (10.f / 8192.f);
  double tl = 0.0, rg = 0.0;
#pragma unroll
  for (int j = 0; j < 4; ++j) {
    const int e = e0 + j;
    const int a = e >> 8, b = e & 255;
    const double v = (double)(((const float*)&s)[j] * sc);
    if (a == b) tl += v;
    else if (b > a) rg += v * v;
  }
  __shared__ double st[256], sr[256];
  st[tid] = tl; sr[tid] = rg;
  __syncthreads();
  for (int w = 128; w > 0; w >>= 1) {
    if (tid < w) { st[tid] += st[tid + w]; sr[tid] += sr[tid + w]; }
    __syncthreads();
  }
  if (tid == 0) { part[blockIdx.x] = st[0]; part[64 + blockIdx.x] = sr[0]; }
}

// ---------- kernel 9: fold 64 block partials -> 2 outputs ----------
__global__ void k_final2(const double* __restrict__ part, float* __restrict__ out) {
  const int lane = threadIdx.x;
  double tl = part[lane];
  double rg = part[64 + lane];
  for (int m = 32; m > 0; m >>= 1) {
    tl += __shfl_xor(tl, m, 64);
    rg += __shfl_xor(rg, m, 64);
  }
  if (lane == 0) {
    out[0] = (float)(-tl);
    out[1] = (float)(rg * 0.05);
  }
}

extern "C" void kernel_launch(void* const* d_in, const int* in_sizes, int n_in,
                              void* d_out, int out_size, void* d_ws, size_t ws_size,
                              hipStream_t stream) {
  const float* FF = (const float*)d_in[0];
  const float* Psi = (const float*)d_in[1];
  float* out = (float*)d_out;
  float* ws = (float*)d_ws;

  size_t o = 0;
  ushort_t* FFbf = (ushort_t*)(ws + o); o += (size_t)N_TOK * D_FEAT / 2;
  float* rn  = ws + o; o += N_TOK;
  float* sqv = ws + o; o += N_TOK;
  float* pd  = ws + o; o += (size_t)N_TOK * NCHUNK * 16;
  int*   pi  = (int*)(ws + o); o += (size_t)N_TOK * NCHUNK * 16;
  float* tv  = ws + o; o += (size_t)N_TOK * KNN;
  int*   tj  = (int*)(ws + o); o += (size_t)N_TOK * KNN;
  int*   cnt = (int*)(ws + o); o += N_TOK;
  double* part = (double*)(ws + o); o += 256;  // 128 doubles
  ushort_t* Gmax = (ushort_t*)(ws + o); o += (size_t)N_TOK * 256 / 2;  // 4 MB
  // region X (32 MB, size of Cs): Cs dead after k_rescore, then reused:
  //   nbrJ (8MB) | nbrW (8MB) | Dv (32KB) | gP (8MB) | Rp (4MB at +25MB)
  char* X = (char*)(ws + o);
  ushort_t* Cs = (ushort_t*)X;
  int*   nbrJ = (int*)X;
  float* nbrW = (float*)(X + (size_t)N_TOK * CAP * 4);
  float* Dv   = (float*)(X + 2 * (size_t)N_TOK * CAP * 4);
  float* gP   = (float*)(X + 2 * (size_t)N_TOK * CAP * 4 + (size_t)N_TOK * 4);
  float* Rp   = (float*)(X + 25ull * 1024 * 1024);

  k_norm<<<N_TOK, 192, 0, stream>>>(FF, FFbf, rn, sqv);
  for (int c = 0; c < NCHUNK; ++c) {
    k_gemm<<<(N_TOK / 128) * (CHUNK / 128), 256, 0, stream>>>(FFbf, Cs, Gmax, c * CHUNK);
    k_sel<<<N_TOK / 4, 256, 0, stream>>>(Cs, Gmax, c, pd, pi);
  }
  k_rescore<<<N_TOK / 4, 256, 0, stream>>>(FF, rn, sqv, pd, pi, tv, tj);
  hipMemsetAsync(cnt, 0, N_TOK * sizeof(int), stream);
  k_scatter<<<(N_TOK * KNN + 255) / 256, 256, 0, stream>>>(tv, tj, cnt, nbrJ, nbrW);
  k_degree<<<N_TOK / 4, 256, 0, stream>>>(cnt, nbrW, Dv);
  k_gpsi<<<N_TOK, 256, 0, stream>>>(Psi, cnt, nbrJ, nbrW, Dv, gP);
  k_Rpart<<<256, 256, 0, stream>>>(Psi, gP, Rp);
  k_Rred<<<64, 256, 0, stream>>>(Rp, part);
  k_final2<<<1, 64, 0, stream>>>(part, out);
}